// Round 6
// baseline (302.505 us; speedup 1.0000x reference)
//
#include <hip/hip_runtime.h>
#include <math.h>
#include <stdint.h>

#define B_     8
#define DIM_   384
#define HEADS_ 8
#define D_     48
#define DH_    24
#define D2_    32
#define HW_    4096
#define IMG    64
#define CH3    1152   // 3*DIM

typedef __attribute__((ext_vector_type(8))) __bf16   bf16x8;
typedef __attribute__((ext_vector_type(4))) float    f32x4;
typedef __attribute__((ext_vector_type(8))) unsigned short u16x8;
typedef __attribute__((ext_vector_type(4))) unsigned short u16x4;

__device__ __forceinline__ float b2f(unsigned short h){
  union { uint32_t u; float f; } v; v.u = ((uint32_t)h) << 16; return v.f;
}
__device__ __forceinline__ unsigned short f2b(float f){
  union { float f; uint32_t u; } v; v.f = f;
  uint32_t r = v.u + 0x7fffu + ((v.u >> 16) & 1u);   // RNE
  return (unsigned short)(r >> 16);
}

// ---------------- reduction helpers ----------------
__device__ __forceinline__ float wred_sum(float v){
#pragma unroll
  for (int m = 32; m; m >>= 1) v += __shfl_xor(v, m);
  return v;
}
__device__ __forceinline__ float wred_max(float v){
#pragma unroll
  for (int m = 32; m; m >>= 1) v = fmaxf(v, __shfl_xor(v, m));
  return v;
}
__device__ __forceinline__ float wred_min(float v){
#pragma unroll
  for (int m = 32; m; m >>= 1) v = fminf(v, __shfl_xor(v, m));
  return v;
}
template<int OP>  // 0=sum 1=max 2=min
__device__ __forceinline__ float block_red(float v, float* lds){
  if (OP == 0) v = wred_sum(v);
  else if (OP == 1) v = wred_max(v);
  else v = wred_min(v);
  const int lane = threadIdx.x & 63;
  const int wid  = threadIdx.x >> 6;
  __syncthreads();
  if (lane == 0) lds[wid] = v;
  __syncthreads();
  const int nw = blockDim.x >> 6;
  float r = lds[0];
  for (int i = 1; i < nw; ++i){
    float o = lds[i];
    if (OP == 0) r += o; else if (OP == 1) r = fmaxf(r, o); else r = fminf(r, o);
  }
  return r;
}

// depthwise 3x3 over 16 px of one image row (x0 % 16 == 0)
__device__ __forceinline__ void dwplane16(const unsigned short* __restrict__ plane,
                                          const float* w9, int y, int x0, float* acc16){
#pragma unroll
  for (int j = 0; j < 16; ++j) acc16[j] = 0.f;
#pragma unroll
  for (int dy = -1; dy <= 1; ++dy){
    const int yy = y + dy;
    if ((unsigned)yy >= (unsigned)IMG) continue;
    const unsigned short* rp = plane + yy * IMG;
    u16x8 C0 = *reinterpret_cast<const u16x8*>(rp + x0);
    u16x8 C1 = *reinterpret_cast<const u16x8*>(rp + x0 + 8);
    float rw[18];
    rw[0]  = (x0 > 0)  ? b2f(rp[x0 - 1])  : 0.f;
    rw[17] = (x0 < 48) ? b2f(rp[x0 + 16]) : 0.f;
#pragma unroll
    for (int j = 0; j < 8; ++j){ rw[1+j] = b2f(C0[j]); rw[9+j] = b2f(C1[j]); }
    const float w0 = w9[(dy+1)*3], w1 = w9[(dy+1)*3+1], w2 = w9[(dy+1)*3+2];
#pragma unroll
    for (int j = 0; j < 16; ++j)
      acc16[j] = fmaf(rw[j], w0, fmaf(rw[j+1], w1, fmaf(rw[j+2], w2, acc16[j])));
  }
}

// depthwise 3x3 over 4 px of one image row (x0 % 4 == 0)
__device__ __forceinline__ void dwplane4(const unsigned short* __restrict__ plane,
                                         const float* w9, int y, int x0, float* acc4){
#pragma unroll
  for (int j = 0; j < 4; ++j) acc4[j] = 0.f;
#pragma unroll
  for (int dy = -1; dy <= 1; ++dy){
    const int yy = y + dy;
    if ((unsigned)yy >= (unsigned)IMG) continue;
    const unsigned short* rp = plane + yy * IMG;
    u16x4 C = *reinterpret_cast<const u16x4*>(rp + x0);
    float rw[6];
    rw[0] = (x0 > 0)  ? b2f(rp[x0 - 1]) : 0.f;
    rw[5] = (x0 < 60) ? b2f(rp[x0 + 4]) : 0.f;
#pragma unroll
    for (int j = 0; j < 4; ++j) rw[1+j] = b2f(C[j]);
    const float w0 = w9[(dy+1)*3], w1 = w9[(dy+1)*3+1], w2 = w9[(dy+1)*3+2];
#pragma unroll
    for (int j = 0; j < 4; ++j)
      acc4[j] = fmaf(rw[j], w0, fmaf(rw[j+1], w1, fmaf(rw[j+2], w2, acc4[j])));
  }
}

// ---------------- P0: w_qkv -> bf16  AND  x -> xT bf16 transpose (merged) ----------------
__global__ __launch_bounds__(256)
void k_prep2(const float* __restrict__ x, const float* __restrict__ w,
             unsigned short* __restrict__ xT, unsigned short* __restrict__ wb){
  __shared__ unsigned short Ts[64][66];
  const int t = threadIdx.x;
  if (blockIdx.x < 432){
    const int i = (blockIdx.x * 256 + t) * 4;    // 1152*384 = 432*256*4
    float4 v = *reinterpret_cast<const float4*>(w + i);
    wb[i+0] = f2b(v.x); wb[i+1] = f2b(v.y); wb[i+2] = f2b(v.z); wb[i+3] = f2b(v.w);
    return;
  }
  const int id = blockIdx.x - 432;               // 8*6*64 = 3072... actually 8*384
  const int bz = id / 384;
  const int r2 = id % 384;
  const int by = r2 / 64, bx = r2 % 64;
  const float* xb = x + ((size_t)bz * DIM_ + by * 64) * HW_ + bx * 64;
#pragma unroll
  for (int rr = 0; rr < 4; ++rr){
    const int r = (t >> 4) + rr * 16;
    const int c = (t & 15) * 4;
    float4 v = *reinterpret_cast<const float4*>(xb + (size_t)r * HW_ + c);
    Ts[r][c+0] = f2b(v.x); Ts[r][c+1] = f2b(v.y); Ts[r][c+2] = f2b(v.z); Ts[r][c+3] = f2b(v.w);
  }
  __syncthreads();
  const int rn = t >> 2, kc = (t & 3) * 16;
  unsigned short* yb = xT + ((size_t)bz * HW_ + bx * 64 + rn) * DIM_ + by * 64 + kc;
  u16x8 o0, o1;
#pragma unroll
  for (int j = 0; j < 8; ++j){ o0[j] = Ts[kc + j][rn]; o1[j] = Ts[kc + 8 + j][rn]; }
  *reinterpret_cast<u16x8*>(yb)     = o0;
  *reinterpret_cast<u16x8*>(yb + 8) = o1;
}

// ---------------- K0: qkv[b,m,n] = sum_k wb[m,k]*xT[b,n,k]  (bf16 MFMA) ----------------
// 128x128 tile, BK=64, 512 threads (8 waves of 32x64), double-buffered LDS,
// counted vmcnt + raw barriers, both-sides XOR chunk swizzle.
__global__ __launch_bounds__(512, 4)
void k_gemm(const unsigned short* __restrict__ wb, const unsigned short* __restrict__ xT,
            unsigned short* __restrict__ qkv){
  const int b  = blockIdx.z;
  const int m0 = blockIdx.y * 128;
  const int n0 = blockIdx.x * 128;
  __shared__ unsigned short As[2][128 * 64];
  __shared__ unsigned short Bs[2][128 * 64];
  const int t = threadIdx.x;
  const int lane = t & 63;
  const int fr = lane & 15;          // fragment row-in-16
  const int ld = lane >> 4;          // 0..3 k-subchunk
  const int w = t >> 6;              // 8 waves: 4x2 of 32x64
  const int wr = w >> 1, wc = w & 1;
  f32x4 acc[2][4];
#pragma unroll
  for (int i = 0; i < 2; ++i)
#pragma unroll
    for (int j = 0; j < 4; ++j) acc[i][j] = (f32x4){0.f,0.f,0.f,0.f};

  const unsigned short* Ag = wb + (size_t)m0 * DIM_;
  const unsigned short* Bg = xT + ((size_t)b * HW_ + n0) * DIM_;

  auto stage = [&](int buf, int k0){
#pragma unroll
    for (int i = 0; i < 2; ++i){
      const int q = i * 512 + t;          // 1024 chunks of 16B
      const int qb = q & ~63;             // wave-uniform base chunk
      const int r = q >> 3, c = q & 7;
      const int cs = c ^ (r & 7);         // pre-swizzled global source
      __builtin_amdgcn_global_load_lds(
        (const __attribute__((address_space(1))) void*)(Ag + (size_t)r * DIM_ + k0 + cs * 8),
        (__attribute__((address_space(3))) void*)(&As[buf][qb * 8]), 16, 0, 0);
    }
#pragma unroll
    for (int i = 0; i < 2; ++i){
      const int q = i * 512 + t;
      const int qb = q & ~63;
      const int r = q >> 3, c = q & 7;
      const int cs = c ^ (r & 7);
      __builtin_amdgcn_global_load_lds(
        (const __attribute__((address_space(1))) void*)(Bg + (size_t)r * DIM_ + k0 + cs * 8),
        (__attribute__((address_space(3))) void*)(&Bs[buf][qb * 8]), 16, 0, 0);
    }
  };

  stage(0, 0);
  for (int it = 0; it < 6; ++it){
    const int cur = it & 1;
    if (it < 5){
      stage(cur ^ 1, (it + 1) * 64);
      asm volatile("s_waitcnt vmcnt(4)" ::: "memory");   // stage(it) done; next 4 in flight
    } else {
      asm volatile("s_waitcnt vmcnt(0)" ::: "memory");
    }
    __builtin_amdgcn_s_barrier();
    asm volatile("" ::: "memory");
#pragma unroll
    for (int ks = 0; ks < 2; ++ks){
      bf16x8 af[2], bfr[4];
#pragma unroll
      for (int mi = 0; mi < 2; ++mi){
        const int row = wr * 32 + mi * 16 + fr;
        const int cc = (ks * 4 + ld) ^ (row & 7);        // swizzled read
        af[mi] = *reinterpret_cast<const bf16x8*>(&As[cur][row * 64 + cc * 8]);
      }
#pragma unroll
      for (int ni = 0; ni < 4; ++ni){
        const int row = wc * 64 + ni * 16 + fr;
        const int cc = (ks * 4 + ld) ^ (row & 7);
        bfr[ni] = *reinterpret_cast<const bf16x8*>(&Bs[cur][row * 64 + cc * 8]);
      }
#pragma unroll
      for (int mi = 0; mi < 2; ++mi)
#pragma unroll
        for (int ni = 0; ni < 4; ++ni)
          acc[mi][ni] = __builtin_amdgcn_mfma_f32_16x16x32_bf16(af[mi], bfr[ni], acc[mi][ni], 0, 0, 0);
    }
    asm volatile("" ::: "memory");
    __builtin_amdgcn_s_barrier();
  }
  unsigned short* yb = qkv + ((size_t)b * CH3 + m0) * HW_ + n0;
#pragma unroll
  for (int mi = 0; mi < 2; ++mi){
    const int rbase = wr * 32 + mi * 16 + (lane >> 4) * 4;
#pragma unroll
    for (int ni = 0; ni < 4; ++ni){
      const int col = wc * 64 + ni * 16 + (lane & 15);
#pragma unroll
      for (int r = 0; r < 4; ++r)
        yb[(size_t)(rbase + r) * HW_ + col] = f2b(acc[mi][ni][r]);
    }
  }
}

// ---------------- K1: dwconv q+k, write p = q*k (bf16) into q-slot, fused stats ----------------
// q,k planes are only ever consumed as the product p; stats from ROUNDED p
// (bit-consistent with k_attn_a's reload). k-planes never written post-GEMM.
__global__ __launch_bounds__(256)
void k_dwqk(unsigned short* __restrict__ qkv, const float* __restrict__ w_dw,
            const float* __restrict__ temperature, const float* __restrict__ w_ar,
            float* __restrict__ prm){
  const int pc = blockIdx.x;               // b*384 + ch
  const int ch = pc % DIM_;
  const int b  = pc / DIM_;
  const int d  = ch % D_;
  const int head = ch / D_;
  unsigned short* qp = qkv + ((size_t)b * CH3 + ch) * HW_;
  const unsigned short* kp = qp + (size_t)DIM_ * HW_;
  const int t  = threadIdx.x;
  const int y  = t >> 2;
  const int x0 = (t & 3) * 16;
  float wq9[9], wk9[9];
#pragma unroll
  for (int i = 0; i < 9; ++i){ wq9[i] = w_dw[ch*9+i]; wk9[i] = w_dw[(DIM_+ch)*9+i]; }
  float aq[16], ak[16];
  dwplane16(qp, wq9, y, x0, aq);
  dwplane16(kp, wk9, y, x0, ak);
  __shared__ float lds[8];
  float pr[16];
  unsigned short pb[16];
  float sq = 0.f, sk = 0.f, pmx = -3.0e38f, pmn = 3.0e38f;
#pragma unroll
  for (int j = 0; j < 16; ++j){
    const float fq = b2f(f2b(aq[j]));
    const float fk = b2f(f2b(ak[j]));
    sq = fmaf(fq, fq, sq); sk = fmaf(fk, fk, sk);
    pb[j] = f2b(fq * fk);
    pr[j] = b2f(pb[j]);
    pmx = fmaxf(pmx, pr[j]); pmn = fminf(pmn, pr[j]);
  }
  sq  = block_red<0>(sq, lds);
  sk  = block_red<0>(sk, lds);
  pmx = block_red<1>(pmx, lds);
  pmn = block_red<2>(pmn, lds);
  const float nq = fmaxf(sqrtf(sq), 1e-12f);
  const float nk = fmaxf(sqrtf(sk), 1e-12f);
  const float c  = temperature[head] / (nq * nk);
  const float m  = (c >= 0.f) ? c * pmx : c * pmn;
  float se = 0.f;
#pragma unroll
  for (int j = 0; j < 16; ++j) se += expf(fmaf(c, pr[j], -m));
  se = block_red<0>(se, lds);
  // block_red syncthreads ensure all q-plane neighborhood reads done before write
  u16x8 o0, o1;
#pragma unroll
  for (int j = 0; j < 8; ++j){ o0[j] = pb[j]; o1[j] = pb[8+j]; }
  *reinterpret_cast<u16x8*>(qp + (size_t)y * IMG + x0)     = o0;
  *reinterpret_cast<u16x8*>(qp + (size_t)y * IMG + x0 + 8) = o1;
  if (t == 0){
    prm[pc*3+0] = c;
    prm[pc*3+1] = m;
    prm[pc*3+2] = w_ar[d] / se;
  }
}

// ---------------- K2: a[n] = sum_d (w_ar[d]/se_d) * exp(c_d*p[d,n] - m_d) ----------------
__global__ __launch_bounds__(256)
void k_attn_a(const unsigned short* __restrict__ dqkv, const float* __restrict__ prm,
              float* __restrict__ abuf){
  const int bh   = blockIdx.y;
  const int head = bh & 7, b = bh >> 3;
  const int t = threadIdx.x;
  const int px0 = (blockIdx.x * 256 + t) * 2;
  __shared__ float pc[D_ * 3];
  for (int i = t; i < D_ * 3; i += 256) pc[i] = prm[bh * (D_ * 3) + i];
  __syncthreads();
  const unsigned short* pbase = dqkv + ((size_t)b * CH3 + head * D_) * HW_ + px0;
  float a0 = 0.f, a1 = 0.f;
  for (int d = 0; d < D_; ++d){
    const uint32_t pv = *reinterpret_cast<const uint32_t*>(pbase + (size_t)d * HW_);
    const float cc = pc[d*3], mm = pc[d*3+1], ww = pc[d*3+2];
    a0 = fmaf(ww, expf(fmaf(cc, b2f((unsigned short)pv), -mm)), a0);
    a1 = fmaf(ww, expf(fmaf(cc, b2f((unsigned short)(pv >> 16)), -mm)), a1);
  }
  float2 o; o.x = a0; o.y = a1;
  *reinterpret_cast<float2*>(abuf + (size_t)bh * HW_ + px0) = o;
}

// ---------------- K3: vctx[b,head,d] = sum_n softmax_n(a)[n] * dwconv(v_d)[n] ----------------
// softmax of the (b,h) row computed in-block from L2-hot abuf; v conv'd on the fly.
__global__ __launch_bounds__(256)
void k_vctx(const unsigned short* __restrict__ qkv, const float* __restrict__ w_dw,
            const float* __restrict__ abuf, float* __restrict__ vctx){
  const int bid  = blockIdx.x;
  const int d    = bid % D_;
  const int head = (bid / D_) % HEADS_;
  const int b    = bid / (D_ * HEADS_);
  const int cv   = 2*DIM_ + head*D_ + d;
  const unsigned short* vp = qkv + ((size_t)b * CH3 + cv) * HW_;
  const float* am = abuf + ((size_t)(b * HEADS_ + head)) * HW_;
  float w9[9];
#pragma unroll
  for (int i = 0; i < 9; ++i) w9[i] = w_dw[cv*9+i];
  __shared__ float lds[8];
  const int t  = threadIdx.x;
  const int y  = t >> 2;
  const int x0 = (t & 3) * 16;
  float a16[16];
#pragma unroll
  for (int i = 0; i < 4; ++i)
    *reinterpret_cast<float4*>(&a16[i*4]) =
      *reinterpret_cast<const float4*>(am + t*16 + i*4);
  float mx = -3.0e38f;
#pragma unroll
  for (int j = 0; j < 16; ++j) mx = fmaxf(mx, a16[j]);
  mx = block_red<1>(mx, lds);
  float e16[16];
  float sl = 0.f;
#pragma unroll
  for (int j = 0; j < 16; ++j){ e16[j] = expf(a16[j] - mx); sl += e16[j]; }
  const float S = block_red<0>(sl, lds);
  const float inv = 1.f / S;
  float dv16[16];
  dwplane16(vp, w9, y, x0, dv16);
  float s = 0.f;
#pragma unroll
  for (int j = 0; j < 16; ++j) s = fmaf(e16[j] * inv, dv16[j], s);
  s = block_red<0>(s, lds);
  if (t == 0) vctx[bid] = s;
}

// ---------------- K4: sp[b,h,n] = sigmoid(sum_d u[d]*dwconv(v_d)[n]) ----------------
// grid (4, 64): block = (b,h, quarter-plane); 4 px/thread; v conv'd on the fly.
__global__ __launch_bounds__(256)
void k_spmask(const unsigned short* __restrict__ qkv, const float* __restrict__ w_dw,
              const float* __restrict__ w_al, const float* __restrict__ w_vl,
              float* __restrict__ spb){
  const int bh   = blockIdx.y;
  const int head = bh & 7, b = bh >> 3;
  const int t = threadIdx.x;
  __shared__ float u[D_];
  __shared__ float avg[DH_];
  __shared__ float wdv[D_*9];
  if (t < DH_){
    float s = 0.f;
    for (int d = 0; d < D_; ++d) s += w_al[t*D_ + d];
    avg[t] = s * (1.f/(float)HW_);
  }
  for (int i = t; i < D_*9; i += 256) wdv[i] = w_dw[(2*DIM_ + head*D_)*9 + i];
  __syncthreads();
  if (t == 0){
    float mx = avg[0];
    for (int o = 1; o < DH_; ++o) mx = fmaxf(mx, avg[o]);
    float s = 0.f;
    for (int o = 0; o < DH_; ++o){ avg[o] = expf(avg[o]-mx); s += avg[o]; }
    const float inv = 1.f/s;
    for (int o = 0; o < DH_; ++o) avg[o] *= inv;
  }
  __syncthreads();
  if (t < D_){
    float s = 0.f;
    for (int o = 0; o < DH_; ++o) s = fmaf(avg[o], w_vl[o*D_ + t], s);
    u[t] = s;
  }
  __syncthreads();
  const int y  = blockIdx.x * 16 + (t >> 4);
  const int x0 = (t & 15) * 4;
  const unsigned short* vb = qkv + ((size_t)b * CH3 + 2*DIM_ + head*D_) * HW_;
  float acc[4] = {0.f, 0.f, 0.f, 0.f};
  for (int d = 0; d < D_; ++d){
    float c4[4];
    dwplane4(vb + (size_t)d * HW_, &wdv[d*9], y, x0, c4);
    const float ud = u[d];
#pragma unroll
    for (int j = 0; j < 4; ++j) acc[j] = fmaf(ud, c4[j], acc[j]);
  }
  float4 o;
  o.x = 1.f/(1.f + expf(-acc[0]));
  o.y = 1.f/(1.f + expf(-acc[1]));
  o.z = 1.f/(1.f + expf(-acc[2]));
  o.w = 1.f/(1.f + expf(-acc[3]));
  *reinterpret_cast<float4*>(spb + (size_t)bh * HW_ + y * IMG + x0) = o;
}

// ---------------- K5: per-b MLP + LayerNorm -> mask_ch[b, c=d*8+head] ----------------
__global__ __launch_bounds__(256)
void k_maskch(const float* __restrict__ vctx, const float* __restrict__ w_vr,
              const float* __restrict__ w_up1, const float* __restrict__ b_up1,
              const float* __restrict__ ln_g, const float* __restrict__ ln_b,
              const float* __restrict__ w_up2, const float* __restrict__ b_up2,
              float* __restrict__ mch){
  const int b = blockIdx.x;
  const int t = threadIdx.x;
  __shared__ float vc[HEADS_*D_];
  __shared__ float cx[HEADS_*DH_];
  __shared__ float t1[D2_*HEADS_];
  __shared__ float lds[8];
  for (int i = t; i < HEADS_*D_; i += 256) vc[i] = vctx[b*HEADS_*D_ + i];
  __syncthreads();
  if (t < HEADS_*DH_){
    const int head = t / DH_, o = t % DH_;
    float s = 0.f;
    for (int d = 0; d < D_; ++d) s = fmaf(w_vr[o*D_+d], vc[head*D_+d], s);
    cx[head*DH_+o] = s;
  }
  __syncthreads();
  const int o2 = t >> 3, hh = t & 7;
  float val = b_up1[o2];
  for (int o = 0; o < DH_; ++o) val = fmaf(w_up1[o2*DH_+o], cx[hh*DH_+o], val);
  const float mu  = block_red<0>(val, lds) * (1.f/256.f);
  const float dv  = val - mu;
  const float var = block_red<0>(dv*dv, lds) * (1.f/256.f);
  float yv = dv / sqrtf(var + 1e-5f);
  yv = fmaf(yv, ln_g[t], ln_b[t]);
  yv = fmaxf(yv, 0.f);
  t1[t] = yv;
  __syncthreads();
  for (int idx = t; idx < D_*HEADS_; idx += 256){
    const int d = idx >> 3, head2 = idx & 7;
    float s = b_up2[d];
    for (int o = 0; o < D2_; ++o) s = fmaf(w_up2[d*D2_+o], t1[o*HEADS_+head2], s);
    mch[b*DIM_ + idx] = 1.f/(1.f + expf(-s));
  }
}

// ---------------- K6: out = x * (mask_ch + sum_h w_proj*sp) ----------------
__global__ __launch_bounds__(256)
void k_out(const float* __restrict__ x, const float* __restrict__ spb,
           const float* __restrict__ mch, const float* __restrict__ w_proj,
           float* __restrict__ out){
  const int b  = blockIdx.z;
  const int c0 = blockIdx.y * 16;
  const int n  = blockIdx.x * 1024 + threadIdx.x * 4;
  float4 sv[8];
#pragma unroll
  for (int h = 0; h < 8; ++h)
    sv[h] = *reinterpret_cast<const float4*>(spb + ((size_t)(b*8+h))*HW_ + n);
  for (int ci = 0; ci < 16; ++ci){
    const int c = c0 + ci;
    const float g = mch[b*DIM_ + c];
    float4 gv; gv.x = g; gv.y = g; gv.z = g; gv.w = g;
#pragma unroll
    for (int h = 0; h < 8; ++h){
      const float wp = w_proj[c*8+h];
      gv.x = fmaf(wp, sv[h].x, gv.x); gv.y = fmaf(wp, sv[h].y, gv.y);
      gv.z = fmaf(wp, sv[h].z, gv.z); gv.w = fmaf(wp, sv[h].w, gv.w);
    }
    const size_t off = ((size_t)b*DIM_ + c)*HW_ + n;
    float4 xv = *reinterpret_cast<const float4*>(x + off);
    xv.x *= gv.x; xv.y *= gv.y; xv.z *= gv.z; xv.w *= gv.w;
    *reinterpret_cast<float4*>(out + off) = xv;
  }
}

extern "C" void kernel_launch(void* const* d_in, const int* in_sizes, int n_in,
                              void* d_out, int out_size, void* d_ws, size_t ws_size,
                              hipStream_t stream) {
  const float* x      = (const float*)d_in[0];
  const float* w_qkv  = (const float*)d_in[1];
  const float* w_dw   = (const float*)d_in[2];
  const float* temp   = (const float*)d_in[3];
  const float* w_ar   = (const float*)d_in[4];
  const float* w_vr   = (const float*)d_in[5];
  const float* w_up1  = (const float*)d_in[6];
  const float* b_up1  = (const float*)d_in[7];
  const float* ln_g   = (const float*)d_in[8];
  const float* ln_b   = (const float*)d_in[9];
  const float* w_up2  = (const float*)d_in[10];
  const float* b_up2  = (const float*)d_in[11];
  const float* w_al   = (const float*)d_in[12];
  const float* w_vl   = (const float*)d_in[13];
  const float* w_proj = (const float*)d_in[14];
  float* out = (float*)d_out;

  unsigned short* qkvb = (unsigned short*)d_ws;              // 8*1152*4096 bf16
  unsigned short* xT   = qkvb + (size_t)B_*CH3*HW_;          // 8*4096*384 bf16
  unsigned short* wb   = xT + (size_t)B_*HW_*DIM_;           // 1152*384 bf16
  float* prm  = (float*)(wb + (size_t)CH3*DIM_);             // 3072*3
  float* abuf = prm + 3*B_*HEADS_*D_;                        // 64*4096
  float* vctx = abuf + (size_t)B_*HEADS_*HW_;                // 3072
  float* spb  = vctx + B_*HEADS_*D_;                         // 64*4096
  float* mch  = spb + (size_t)B_*HEADS_*HW_;                 // 8*384

  k_prep2<<<dim3(432 + B_*6*64), 256, 0, stream>>>(x, w_qkv, xT, wb);
  k_gemm<<<dim3(HW_/128, CH3/128, B_), 512, 0, stream>>>(wb, xT, qkvb);
  k_dwqk<<<dim3(B_*DIM_), 256, 0, stream>>>(qkvb, w_dw, temp, w_ar, prm);
  k_attn_a<<<dim3(8, B_*HEADS_), 256, 0, stream>>>(qkvb, prm, abuf);
  k_vctx<<<dim3(B_*HEADS_*D_), 256, 0, stream>>>(qkvb, w_dw, abuf, vctx);
  k_spmask<<<dim3(4, B_*HEADS_), 256, 0, stream>>>(qkvb, w_dw, w_al, w_vl, spb);
  k_maskch<<<dim3(B_), 256, 0, stream>>>(vctx, w_vr, w_up1, b_up1, ln_g, ln_b,
                                         w_up2, b_up2, mch);
  k_out<<<dim3(HW_/1024, DIM_/16, B_), 256, 0, stream>>>(x, spb, mch, w_proj, out);
}

// Round 7
// 249.268 us; speedup vs baseline: 1.2136x; 1.2136x over previous
//
#include <hip/hip_runtime.h>
#include <math.h>
#include <stdint.h>

#define B_     8
#define DIM_   384
#define HEADS_ 8
#define D_     48
#define DH_    24
#define D2_    32
#define HW_    4096
#define IMG    64
#define CH3    1152   // 3*DIM

typedef __attribute__((ext_vector_type(8))) __bf16   bf16x8;
typedef __attribute__((ext_vector_type(4))) float    f32x4;
typedef __attribute__((ext_vector_type(8))) unsigned short u16x8;

__device__ __forceinline__ float b2f(unsigned short h){
  union { uint32_t u; float f; } v; v.u = ((uint32_t)h) << 16; return v.f;
}
__device__ __forceinline__ unsigned short f2b(float f){
  union { float f; uint32_t u; } v; v.f = f;
  uint32_t r = v.u + 0x7fffu + ((v.u >> 16) & 1u);   // RNE
  return (unsigned short)(r >> 16);
}

// ---------------- reduction helpers ----------------
__device__ __forceinline__ float wred_sum(float v){
#pragma unroll
  for (int m = 32; m; m >>= 1) v += __shfl_xor(v, m);
  return v;
}
__device__ __forceinline__ float wred_max(float v){
#pragma unroll
  for (int m = 32; m; m >>= 1) v = fmaxf(v, __shfl_xor(v, m));
  return v;
}
__device__ __forceinline__ float wred_min(float v){
#pragma unroll
  for (int m = 32; m; m >>= 1) v = fminf(v, __shfl_xor(v, m));
  return v;
}
template<int OP>  // 0=sum 1=max 2=min
__device__ __forceinline__ float block_red(float v, float* lds){
  if (OP == 0) v = wred_sum(v);
  else if (OP == 1) v = wred_max(v);
  else v = wred_min(v);
  const int lane = threadIdx.x & 63;
  const int wid  = threadIdx.x >> 6;
  __syncthreads();
  if (lane == 0) lds[wid] = v;
  __syncthreads();
  const int nw = blockDim.x >> 6;
  float r = lds[0];
  for (int i = 1; i < nw; ++i){
    float o = lds[i];
    if (OP == 0) r += o; else if (OP == 1) r = fmaxf(r, o); else r = fminf(r, o);
  }
  return r;
}

// depthwise 3x3 over 16 px of one image row (x0 % 16 == 0)
__device__ __forceinline__ void dwplane16(const unsigned short* __restrict__ plane,
                                          const float* w9, int y, int x0, float* acc16){
#pragma unroll
  for (int j = 0; j < 16; ++j) acc16[j] = 0.f;
#pragma unroll
  for (int dy = -1; dy <= 1; ++dy){
    const int yy = y + dy;
    if ((unsigned)yy >= (unsigned)IMG) continue;
    const unsigned short* rp = plane + yy * IMG;
    u16x8 C0 = *reinterpret_cast<const u16x8*>(rp + x0);
    u16x8 C1 = *reinterpret_cast<const u16x8*>(rp + x0 + 8);
    float rw[18];
    rw[0]  = (x0 > 0)  ? b2f(rp[x0 - 1])  : 0.f;
    rw[17] = (x0 < 48) ? b2f(rp[x0 + 16]) : 0.f;
#pragma unroll
    for (int j = 0; j < 8; ++j){ rw[1+j] = b2f(C0[j]); rw[9+j] = b2f(C1[j]); }
    const float w0 = w9[(dy+1)*3], w1 = w9[(dy+1)*3+1], w2 = w9[(dy+1)*3+2];
#pragma unroll
    for (int j = 0; j < 16; ++j)
      acc16[j] = fmaf(rw[j], w0, fmaf(rw[j+1], w1, fmaf(rw[j+2], w2, acc16[j])));
  }
}

// ---------------- P0: w_qkv -> bf16  AND  x -> xT bf16 transpose (merged) ----------------
__global__ __launch_bounds__(256)
void k_prep2(const float* __restrict__ x, const float* __restrict__ w,
             unsigned short* __restrict__ xT, unsigned short* __restrict__ wb){
  __shared__ unsigned short Ts[64][66];
  const int t = threadIdx.x;
  if (blockIdx.x < 432){
    const int i = (blockIdx.x * 256 + t) * 4;    // 1152*384 = 432*256*4
    float4 v = *reinterpret_cast<const float4*>(w + i);
    wb[i+0] = f2b(v.x); wb[i+1] = f2b(v.y); wb[i+2] = f2b(v.z); wb[i+3] = f2b(v.w);
    return;
  }
  const int id = blockIdx.x - 432;               // 8*384 tiles
  const int bz = id / 384;
  const int r2 = id % 384;
  const int by = r2 / 64, bx = r2 % 64;
  const float* xb = x + ((size_t)bz * DIM_ + by * 64) * HW_ + bx * 64;
#pragma unroll
  for (int rr = 0; rr < 4; ++rr){
    const int r = (t >> 4) + rr * 16;
    const int c = (t & 15) * 4;
    float4 v = *reinterpret_cast<const float4*>(xb + (size_t)r * HW_ + c);
    Ts[r][c+0] = f2b(v.x); Ts[r][c+1] = f2b(v.y); Ts[r][c+2] = f2b(v.z); Ts[r][c+3] = f2b(v.w);
  }
  __syncthreads();
  const int rn = t >> 2, kc = (t & 3) * 16;
  unsigned short* yb = xT + ((size_t)bz * HW_ + bx * 64 + rn) * DIM_ + by * 64 + kc;
  u16x8 o0, o1;
#pragma unroll
  for (int j = 0; j < 8; ++j){ o0[j] = Ts[kc + j][rn]; o1[j] = Ts[kc + 8 + j][rn]; }
  *reinterpret_cast<u16x8*>(yb)     = o0;
  *reinterpret_cast<u16x8*>(yb + 8) = o1;
}

// ---------------- K0: qkv[b,m,n] = sum_k wb[m,k]*xT[b,n,k]  (bf16 MFMA) ----------------
// 128x128 tile, BK=64, 512 threads (8 waves of 32x64), double-buffered LDS,
// counted vmcnt + raw barriers, both-sides XOR chunk swizzle.
__global__ __launch_bounds__(512, 4)
void k_gemm(const unsigned short* __restrict__ wb, const unsigned short* __restrict__ xT,
            unsigned short* __restrict__ qkv){
  const int b  = blockIdx.z;
  const int m0 = blockIdx.y * 128;
  const int n0 = blockIdx.x * 128;
  __shared__ unsigned short As[2][128 * 64];
  __shared__ unsigned short Bs[2][128 * 64];
  const int t = threadIdx.x;
  const int lane = t & 63;
  const int fr = lane & 15;          // fragment row-in-16
  const int ld = lane >> 4;          // 0..3 k-subchunk
  const int w = t >> 6;              // 8 waves: 4x2 of 32x64
  const int wr = w >> 1, wc = w & 1;
  f32x4 acc[2][4];
#pragma unroll
  for (int i = 0; i < 2; ++i)
#pragma unroll
    for (int j = 0; j < 4; ++j) acc[i][j] = (f32x4){0.f,0.f,0.f,0.f};

  const unsigned short* Ag = wb + (size_t)m0 * DIM_;
  const unsigned short* Bg = xT + ((size_t)b * HW_ + n0) * DIM_;

  auto stage = [&](int buf, int k0){
#pragma unroll
    for (int i = 0; i < 2; ++i){
      const int q = i * 512 + t;          // 1024 chunks of 16B
      const int qb = q & ~63;             // wave-uniform base chunk
      const int r = q >> 3, c = q & 7;
      const int cs = c ^ (r & 7);         // pre-swizzled global source
      __builtin_amdgcn_global_load_lds(
        (const __attribute__((address_space(1))) void*)(Ag + (size_t)r * DIM_ + k0 + cs * 8),
        (__attribute__((address_space(3))) void*)(&As[buf][qb * 8]), 16, 0, 0);
    }
#pragma unroll
    for (int i = 0; i < 2; ++i){
      const int q = i * 512 + t;
      const int qb = q & ~63;
      const int r = q >> 3, c = q & 7;
      const int cs = c ^ (r & 7);
      __builtin_amdgcn_global_load_lds(
        (const __attribute__((address_space(1))) void*)(Bg + (size_t)r * DIM_ + k0 + cs * 8),
        (__attribute__((address_space(3))) void*)(&Bs[buf][qb * 8]), 16, 0, 0);
    }
  };

  stage(0, 0);
  for (int it = 0; it < 6; ++it){
    const int cur = it & 1;
    if (it < 5){
      stage(cur ^ 1, (it + 1) * 64);
      asm volatile("s_waitcnt vmcnt(4)" ::: "memory");   // stage(it) done; next 4 in flight
    } else {
      asm volatile("s_waitcnt vmcnt(0)" ::: "memory");
    }
    __builtin_amdgcn_s_barrier();
    asm volatile("" ::: "memory");
#pragma unroll
    for (int ks = 0; ks < 2; ++ks){
      bf16x8 af[2], bfr[4];
#pragma unroll
      for (int mi = 0; mi < 2; ++mi){
        const int row = wr * 32 + mi * 16 + fr;
        const int cc = (ks * 4 + ld) ^ (row & 7);        // swizzled read
        af[mi] = *reinterpret_cast<const bf16x8*>(&As[cur][row * 64 + cc * 8]);
      }
#pragma unroll
      for (int ni = 0; ni < 4; ++ni){
        const int row = wc * 64 + ni * 16 + fr;
        const int cc = (ks * 4 + ld) ^ (row & 7);
        bfr[ni] = *reinterpret_cast<const bf16x8*>(&Bs[cur][row * 64 + cc * 8]);
      }
#pragma unroll
      for (int mi = 0; mi < 2; ++mi)
#pragma unroll
        for (int ni = 0; ni < 4; ++ni)
          acc[mi][ni] = __builtin_amdgcn_mfma_f32_16x16x32_bf16(af[mi], bfr[ni], acc[mi][ni], 0, 0, 0);
    }
    asm volatile("" ::: "memory");
    __builtin_amdgcn_s_barrier();
  }
  unsigned short* yb = qkv + ((size_t)b * CH3 + m0) * HW_ + n0;
#pragma unroll
  for (int mi = 0; mi < 2; ++mi){
    const int rbase = wr * 32 + mi * 16 + (lane >> 4) * 4;
#pragma unroll
    for (int ni = 0; ni < 4; ++ni){
      const int col = wc * 64 + ni * 16 + (lane & 15);
#pragma unroll
      for (int r = 0; r < 4; ++r)
        yb[(size_t)(rbase + r) * HW_ + col] = f2b(acc[mi][ni][r]);
    }
  }
}

// ---------------- K1: dwconv q,k,v; write p=q*k (q-slot) + dv (v-slot); fused stats ----------------
__global__ __launch_bounds__(256)
void k_dwqkv(unsigned short* __restrict__ qkv, const float* __restrict__ w_dw,
             const float* __restrict__ temperature, const float* __restrict__ w_ar,
             float* __restrict__ prm){
  const int pc = blockIdx.x;               // b*384 + ch
  const int ch = pc % DIM_;
  const int b  = pc / DIM_;
  const int d  = ch % D_;
  const int head = ch / D_;
  unsigned short* qp = qkv + ((size_t)b * CH3 + ch) * HW_;
  const unsigned short* kp = qp + (size_t)DIM_ * HW_;
  unsigned short* vp = qp + (size_t)(2 * DIM_) * HW_;
  const int t  = threadIdx.x;
  const int y  = t >> 2;
  const int x0 = (t & 3) * 16;
  float wq9[9], wk9[9], wv9[9];
#pragma unroll
  for (int i = 0; i < 9; ++i){
    wq9[i] = w_dw[ch*9+i];
    wk9[i] = w_dw[(DIM_+ch)*9+i];
    wv9[i] = w_dw[(2*DIM_+ch)*9+i];
  }
  float aq[16], ak[16], av[16];
  dwplane16(qp, wq9, y, x0, aq);
  dwplane16(kp, wk9, y, x0, ak);
  dwplane16(vp, wv9, y, x0, av);
  __shared__ float lds[8];
  float pr[16];
  unsigned short pb[16];
  float sq = 0.f, sk = 0.f, pmx = -3.0e38f, pmn = 3.0e38f;
#pragma unroll
  for (int j = 0; j < 16; ++j){
    const float fq = b2f(f2b(aq[j]));
    const float fk = b2f(f2b(ak[j]));
    sq = fmaf(fq, fq, sq); sk = fmaf(fk, fk, sk);
    pb[j] = f2b(fq * fk);
    pr[j] = b2f(pb[j]);
    pmx = fmaxf(pmx, pr[j]); pmn = fminf(pmn, pr[j]);
  }
  sq  = block_red<0>(sq, lds);
  sk  = block_red<0>(sk, lds);
  pmx = block_red<1>(pmx, lds);
  pmn = block_red<2>(pmn, lds);
  const float nq = fmaxf(sqrtf(sq), 1e-12f);
  const float nk = fmaxf(sqrtf(sk), 1e-12f);
  const float c  = temperature[head] / (nq * nk);
  const float m  = (c >= 0.f) ? c * pmx : c * pmn;
  float se = 0.f;
#pragma unroll
  for (int j = 0; j < 16; ++j) se += expf(fmaf(c, pr[j], -m));
  se = block_red<0>(se, lds);
  // block_red syncthreads guarantee all q/v neighborhood reads complete before writes
  u16x8 o0, o1;
#pragma unroll
  for (int j = 0; j < 8; ++j){ o0[j] = pb[j]; o1[j] = pb[8+j]; }
  *reinterpret_cast<u16x8*>(qp + (size_t)y * IMG + x0)     = o0;
  *reinterpret_cast<u16x8*>(qp + (size_t)y * IMG + x0 + 8) = o1;
#pragma unroll
  for (int j = 0; j < 8; ++j){ o0[j] = f2b(av[j]); o1[j] = f2b(av[8+j]); }
  *reinterpret_cast<u16x8*>(vp + (size_t)y * IMG + x0)     = o0;
  *reinterpret_cast<u16x8*>(vp + (size_t)y * IMG + x0 + 8) = o1;
  if (t == 0){
    prm[pc*3+0] = c;
    prm[pc*3+1] = m;
    prm[pc*3+2] = w_ar[d] / se;
  }
}

// ---------------- K2: a[n] = sum_d (w_ar[d]/se_d) * exp(c_d*p[d,n] - m_d) ----------------
__global__ __launch_bounds__(256)
void k_attn_a(const unsigned short* __restrict__ dqkv, const float* __restrict__ prm,
              float* __restrict__ abuf){
  const int bh   = blockIdx.y;
  const int head = bh & 7, b = bh >> 3;
  const int t = threadIdx.x;
  const int px0 = (blockIdx.x * 256 + t) * 2;
  __shared__ float pc[D_ * 3];
  for (int i = t; i < D_ * 3; i += 256) pc[i] = prm[bh * (D_ * 3) + i];
  __syncthreads();
  const unsigned short* pbase = dqkv + ((size_t)b * CH3 + head * D_) * HW_ + px0;
  float a0 = 0.f, a1 = 0.f;
  for (int d = 0; d < D_; ++d){
    const uint32_t pv = *reinterpret_cast<const uint32_t*>(pbase + (size_t)d * HW_);
    const float cc = pc[d*3], mm = pc[d*3+1], ww = pc[d*3+2];
    a0 = fmaf(ww, expf(fmaf(cc, b2f((unsigned short)pv), -mm)), a0);
    a1 = fmaf(ww, expf(fmaf(cc, b2f((unsigned short)(pv >> 16)), -mm)), a1);
  }
  float2 o; o.x = a0; o.y = a1;
  *reinterpret_cast<float2*>(abuf + (size_t)bh * HW_ + px0) = o;
}

// ---------------- K3: vctx[b,head,d] = sum_n softmax_n(a)[n] * dv[d,n] ----------------
// softmax params recomputed in-block from L2-hot abuf; dv streamed (u16x8).
__global__ __launch_bounds__(256)
void k_vctx(const unsigned short* __restrict__ dqkv, const float* __restrict__ abuf,
            float* __restrict__ vctx){
  const int bid  = blockIdx.x;
  const int d    = bid % D_;
  const int head = (bid / D_) % HEADS_;
  const int b    = bid / (D_ * HEADS_);
  const unsigned short* vp = dqkv + ((size_t)b * CH3 + 2*DIM_ + head*D_ + d) * HW_;
  const float* am = abuf + ((size_t)(b * HEADS_ + head)) * HW_;
  __shared__ float lds[8];
  const int t = threadIdx.x;
  float a16[16];
#pragma unroll
  for (int i = 0; i < 4; ++i)
    *reinterpret_cast<float4*>(&a16[i*4]) =
      *reinterpret_cast<const float4*>(am + t*16 + i*4);
  float mx = -3.0e38f;
#pragma unroll
  for (int j = 0; j < 16; ++j) mx = fmaxf(mx, a16[j]);
  mx = block_red<1>(mx, lds);
  float e16[16];
  float sl = 0.f;
#pragma unroll
  for (int j = 0; j < 16; ++j){ e16[j] = expf(a16[j] - mx); sl += e16[j]; }
  const float S = block_red<0>(sl, lds);
  const float inv = 1.f / S;
  u16x8 v0 = *reinterpret_cast<const u16x8*>(vp + t * 16);
  u16x8 v1 = *reinterpret_cast<const u16x8*>(vp + t * 16 + 8);
  float s = 0.f;
#pragma unroll
  for (int j = 0; j < 8; ++j) s = fmaf(e16[j] * inv,     b2f(v0[j]), s);
#pragma unroll
  for (int j = 0; j < 8; ++j) s = fmaf(e16[8+j] * inv, b2f(v1[j]), s);
  s = block_red<0>(s, lds);
  if (t == 0) vctx[bid] = s;
}

// ---------------- K4: sp[b,h,n] = sigmoid(sum_d u[d]*dv[d,n]) ----------------
// grid (8, 64): 512 blocks, 2 px/thread, streaming uint32 loads of dv.
__global__ __launch_bounds__(256)
void k_spmask(const unsigned short* __restrict__ dqkv, const float* __restrict__ w_al,
              const float* __restrict__ w_vl, float* __restrict__ spb){
  const int bh   = blockIdx.y;
  const int head = bh & 7, b = bh >> 3;
  const int t = threadIdx.x;
  const int px0 = (blockIdx.x * 256 + t) * 2;
  __shared__ float u[D_];
  __shared__ float avg[DH_];
  if (t < DH_){
    float s = 0.f;
    for (int d = 0; d < D_; ++d) s += w_al[t*D_ + d];
    avg[t] = s * (1.f/(float)HW_);
  }
  __syncthreads();
  if (t == 0){
    float mx = avg[0];
    for (int o = 1; o < DH_; ++o) mx = fmaxf(mx, avg[o]);
    float s = 0.f;
    for (int o = 0; o < DH_; ++o){ avg[o] = expf(avg[o]-mx); s += avg[o]; }
    const float inv = 1.f/s;
    for (int o = 0; o < DH_; ++o) avg[o] *= inv;
  }
  __syncthreads();
  if (t < D_){
    float s = 0.f;
    for (int o = 0; o < DH_; ++o) s = fmaf(avg[o], w_vl[o*D_ + t], s);
    u[t] = s;
  }
  __syncthreads();
  const unsigned short* vb = dqkv + ((size_t)b * CH3 + 2*DIM_ + head*D_) * HW_ + px0;
  float a0 = 0.f, a1 = 0.f;
  for (int d = 0; d < D_; ++d){
    const uint32_t vv = *reinterpret_cast<const uint32_t*>(vb + (size_t)d * HW_);
    const float ud = u[d];
    a0 = fmaf(ud, b2f((unsigned short)vv), a0);
    a1 = fmaf(ud, b2f((unsigned short)(vv >> 16)), a1);
  }
  float2 o;
  o.x = 1.f/(1.f + expf(-a0));
  o.y = 1.f/(1.f + expf(-a1));
  *reinterpret_cast<float2*>(spb + (size_t)bh * HW_ + px0) = o;
}

// ---------------- K5: per-b MLP + LayerNorm -> mask_ch[b, c=d*8+head] ----------------
__global__ __launch_bounds__(256)
void k_maskch(const float* __restrict__ vctx, const float* __restrict__ w_vr,
              const float* __restrict__ w_up1, const float* __restrict__ b_up1,
              const float* __restrict__ ln_g, const float* __restrict__ ln_b,
              const float* __restrict__ w_up2, const float* __restrict__ b_up2,
              float* __restrict__ mch){
  const int b = blockIdx.x;
  const int t = threadIdx.x;
  __shared__ float vc[HEADS_*D_];
  __shared__ float cx[HEADS_*DH_];
  __shared__ float t1[D2_*HEADS_];
  __shared__ float lds[8];
  for (int i = t; i < HEADS_*D_; i += 256) vc[i] = vctx[b*HEADS_*D_ + i];
  __syncthreads();
  if (t < HEADS_*DH_){
    const int head = t / DH_, o = t % DH_;
    float s = 0.f;
    for (int d = 0; d < D_; ++d) s = fmaf(w_vr[o*D_+d], vc[head*D_+d], s);
    cx[head*DH_+o] = s;
  }
  __syncthreads();
  const int o2 = t >> 3, hh = t & 7;
  float val = b_up1[o2];
  for (int o = 0; o < DH_; ++o) val = fmaf(w_up1[o2*DH_+o], cx[hh*DH_+o], val);
  const float mu  = block_red<0>(val, lds) * (1.f/256.f);
  const float dv  = val - mu;
  const float var = block_red<0>(dv*dv, lds) * (1.f/256.f);
  float yv = dv / sqrtf(var + 1e-5f);
  yv = fmaf(yv, ln_g[t], ln_b[t]);
  yv = fmaxf(yv, 0.f);
  t1[t] = yv;
  __syncthreads();
  for (int idx = t; idx < D_*HEADS_; idx += 256){
    const int d = idx >> 3, head2 = idx & 7;
    float s = b_up2[d];
    for (int o = 0; o < D2_; ++o) s = fmaf(w_up2[d*D2_+o], t1[o*HEADS_+head2], s);
    mch[b*DIM_ + idx] = 1.f/(1.f + expf(-s));
  }
}

// ---------------- K6: out = x * (mask_ch + sum_h w_proj*sp) ----------------
__global__ __launch_bounds__(256)
void k_out(const float* __restrict__ x, const float* __restrict__ spb,
           const float* __restrict__ mch, const float* __restrict__ w_proj,
           float* __restrict__ out){
  const int b  = blockIdx.z;
  const int c0 = blockIdx.y * 16;
  const int n  = blockIdx.x * 1024 + threadIdx.x * 4;
  float4 sv[8];
#pragma unroll
  for (int h = 0; h < 8; ++h)
    sv[h] = *reinterpret_cast<const float4*>(spb + ((size_t)(b*8+h))*HW_ + n);
  for (int ci = 0; ci < 16; ++ci){
    const int c = c0 + ci;
    const float g = mch[b*DIM_ + c];
    float4 gv; gv.x = g; gv.y = g; gv.z = g; gv.w = g;
#pragma unroll
    for (int h = 0; h < 8; ++h){
      const float wp = w_proj[c*8+h];
      gv.x = fmaf(wp, sv[h].x, gv.x); gv.y = fmaf(wp, sv[h].y, gv.y);
      gv.z = fmaf(wp, sv[h].z, gv.z); gv.w = fmaf(wp, sv[h].w, gv.w);
    }
    const size_t off = ((size_t)b*DIM_ + c)*HW_ + n;
    float4 xv = *reinterpret_cast<const float4*>(x + off);
    xv.x *= gv.x; xv.y *= gv.y; xv.z *= gv.z; xv.w *= gv.w;
    *reinterpret_cast<float4*>(out + off) = xv;
  }
}

extern "C" void kernel_launch(void* const* d_in, const int* in_sizes, int n_in,
                              void* d_out, int out_size, void* d_ws, size_t ws_size,
                              hipStream_t stream) {
  const float* x      = (const float*)d_in[0];
  const float* w_qkv  = (const float*)d_in[1];
  const float* w_dw   = (const float*)d_in[2];
  const float* temp   = (const float*)d_in[3];
  const float* w_ar   = (const float*)d_in[4];
  const float* w_vr   = (const float*)d_in[5];
  const float* w_up1  = (const float*)d_in[6];
  const float* b_up1  = (const float*)d_in[7];
  const float* ln_g   = (const float*)d_in[8];
  const float* ln_b   = (const float*)d_in[9];
  const float* w_up2  = (const float*)d_in[10];
  const float* b_up2  = (const float*)d_in[11];
  const float* w_al   = (const float*)d_in[12];
  const float* w_vl   = (const float*)d_in[13];
  const float* w_proj = (const float*)d_in[14];
  float* out = (float*)d_out;

  unsigned short* qkvb = (unsigned short*)d_ws;              // 8*1152*4096 bf16
  unsigned short* xT   = qkvb + (size_t)B_*CH3*HW_;          // 8*4096*384 bf16
  unsigned short* wb   = xT + (size_t)B_*HW_*DIM_;           // 1152*384 bf16
  float* prm  = (float*)(wb + (size_t)CH3*DIM_);             // 3072*3
  float* abuf = prm + 3*B_*HEADS_*D_;                        // 64*4096
  float* vctx = abuf + (size_t)B_*HEADS_*HW_;                // 3072
  float* spb  = vctx + B_*HEADS_*D_;                         // 64*4096
  float* mch  = spb + (size_t)B_*HEADS_*HW_;                 // 8*384

  k_prep2<<<dim3(432 + B_*384), 256, 0, stream>>>(x, w_qkv, xT, wb);
  k_gemm<<<dim3(HW_/128, CH3/128, B_), 512, 0, stream>>>(wb, xT, qkvb);
  k_dwqkv<<<dim3(B_*DIM_), 256, 0, stream>>>(qkvb, w_dw, temp, w_ar, prm);
  k_attn_a<<<dim3(8, B_*HEADS_), 256, 0, stream>>>(qkvb, prm, abuf);
  k_vctx<<<dim3(B_*HEADS_*D_), 256, 0, stream>>>(qkvb, abuf, vctx);
  k_spmask<<<dim3(8, B_*HEADS_), 256, 0, stream>>>(qkvb, w_al, w_vl, spb);
  k_maskch<<<dim3(B_), 256, 0, stream>>>(vctx, w_vr, w_up1, b_up1, ln_g, ln_b,
                                         w_up2, b_up2, mch);
  k_out<<<dim3(HW_/1024, DIM_/16, B_), 256, 0, stream>>>(x, spb, mch, w_proj, out);
}

// Round 9
// 242.435 us; speedup vs baseline: 1.2478x; 1.0282x over previous
//
#include <hip/hip_runtime.h>
#include <math.h>
#include <stdint.h>

#define B_     8
#define DIM_   384
#define HEADS_ 8
#define D_     48
#define DH_    24
#define D2_    32
#define HW_    4096
#define IMG    64
#define CH3    1152   // 3*DIM

typedef __attribute__((ext_vector_type(8))) __bf16   bf16x8;
typedef __attribute__((ext_vector_type(4))) float    f32x4;
typedef __attribute__((ext_vector_type(8))) unsigned short u16x8;

__device__ __forceinline__ float b2f(unsigned short h){
  union { uint32_t u; float f; } v; v.u = ((uint32_t)h) << 16; return v.f;
}
// HW RNE bf16 convert — compiler packs pairs into v_cvt_pk_bf16_f32
__device__ __forceinline__ unsigned short f2b(float f){
  return __builtin_bit_cast(unsigned short, (__bf16)f);
}

// ---------------- reduction helpers ----------------
__device__ __forceinline__ float wred_sum(float v){
#pragma unroll
  for (int m = 32; m; m >>= 1) v += __shfl_xor(v, m);
  return v;
}
template<int OP>  // 0=sum 1=max 2=min
__device__ __forceinline__ float block_red(float v, float* lds){
  if (OP == 0) v = wred_sum(v);
  else if (OP == 1){
#pragma unroll
    for (int m = 32; m; m >>= 1) v = fmaxf(v, __shfl_xor(v, m));
  } else {
#pragma unroll
    for (int m = 32; m; m >>= 1) v = fminf(v, __shfl_xor(v, m));
  }
  const int lane = threadIdx.x & 63;
  const int wid  = threadIdx.x >> 6;
  __syncthreads();
  if (lane == 0) lds[wid] = v;
  __syncthreads();
  const int nw = blockDim.x >> 6;
  float r = lds[0];
  for (int i = 1; i < nw; ++i){
    float o = lds[i];
    if (OP == 0) r += o; else if (OP == 1) r = fmaxf(r, o); else r = fminf(r, o);
  }
  return r;
}

// packed {sum,sum,max,min} block reduction — ONE barrier round (256 threads)
__device__ __forceinline__ void block_red4(float& s0, float& s1, float& mx, float& mn,
                                           float* lds /*>=16 floats*/){
#pragma unroll
  for (int m = 32; m; m >>= 1){
    s0 += __shfl_xor(s0, m);
    s1 += __shfl_xor(s1, m);
    mx = fmaxf(mx, __shfl_xor(mx, m));
    mn = fminf(mn, __shfl_xor(mn, m));
  }
  const int lane = threadIdx.x & 63;
  const int wid  = threadIdx.x >> 6;
  __syncthreads();
  if (lane == 0){
    lds[wid*4+0] = s0; lds[wid*4+1] = s1; lds[wid*4+2] = mx; lds[wid*4+3] = mn;
  }
  __syncthreads();
  s0 = lds[0] + lds[4] + lds[8]  + lds[12];
  s1 = lds[1] + lds[5] + lds[9]  + lds[13];
  mx = fmaxf(fmaxf(lds[2], lds[6]), fmaxf(lds[10], lds[14]));
  mn = fminf(fminf(lds[3], lds[7]), fminf(lds[11], lds[15]));
}

// depthwise 3x3 over 16 px of one image row (x0 % 16 == 0)
__device__ __forceinline__ void dwplane16(const unsigned short* __restrict__ plane,
                                          const float* w9, int y, int x0, float* acc16){
#pragma unroll
  for (int j = 0; j < 16; ++j) acc16[j] = 0.f;
#pragma unroll
  for (int dy = -1; dy <= 1; ++dy){
    const int yy = y + dy;
    if ((unsigned)yy >= (unsigned)IMG) continue;
    const unsigned short* rp = plane + yy * IMG;
    u16x8 C0 = *reinterpret_cast<const u16x8*>(rp + x0);
    u16x8 C1 = *reinterpret_cast<const u16x8*>(rp + x0 + 8);
    float rw[18];
    rw[0]  = (x0 > 0)  ? b2f(rp[x0 - 1])  : 0.f;
    rw[17] = (x0 < 48) ? b2f(rp[x0 + 16]) : 0.f;
#pragma unroll
    for (int j = 0; j < 8; ++j){ rw[1+j] = b2f(C0[j]); rw[9+j] = b2f(C1[j]); }
    const float w0 = w9[(dy+1)*3], w1 = w9[(dy+1)*3+1], w2 = w9[(dy+1)*3+2];
#pragma unroll
    for (int j = 0; j < 16; ++j)
      acc16[j] = fmaf(rw[j], w0, fmaf(rw[j+1], w1, fmaf(rw[j+2], w2, acc16[j])));
  }
}

// ---------------- P0: w_qkv -> bf16  AND  x -> xT bf16 transpose (merged) ----------------
__global__ __launch_bounds__(256)
void k_prep2(const float* __restrict__ x, const float* __restrict__ w,
             unsigned short* __restrict__ xT, unsigned short* __restrict__ wb){
  __shared__ unsigned short Ts[64][66];
  const int t = threadIdx.x;
  if (blockIdx.x < 432){
    const int i = (blockIdx.x * 256 + t) * 4;    // 1152*384 = 432*256*4
    float4 v = *reinterpret_cast<const float4*>(w + i);
    wb[i+0] = f2b(v.x); wb[i+1] = f2b(v.y); wb[i+2] = f2b(v.z); wb[i+3] = f2b(v.w);
    return;
  }
  const int id = blockIdx.x - 432;               // 8*384 tiles
  const int bz = id / 384;
  const int r2 = id % 384;
  const int by = r2 / 64, bx = r2 % 64;
  const float* xb = x + ((size_t)bz * DIM_ + by * 64) * HW_ + bx * 64;
#pragma unroll
  for (int rr = 0; rr < 4; ++rr){
    const int r = (t >> 4) + rr * 16;
    const int c = (t & 15) * 4;
    float4 v = *reinterpret_cast<const float4*>(xb + (size_t)r * HW_ + c);
    Ts[r][c+0] = f2b(v.x); Ts[r][c+1] = f2b(v.y); Ts[r][c+2] = f2b(v.z); Ts[r][c+3] = f2b(v.w);
  }
  __syncthreads();
  const int rn = t >> 2, kc = (t & 3) * 16;
  unsigned short* yb = xT + ((size_t)bz * HW_ + bx * 64 + rn) * DIM_ + by * 64 + kc;
  u16x8 o0, o1;
#pragma unroll
  for (int j = 0; j < 8; ++j){ o0[j] = Ts[kc + j][rn]; o1[j] = Ts[kc + 8 + j][rn]; }
  *reinterpret_cast<u16x8*>(yb)     = o0;
  *reinterpret_cast<u16x8*>(yb + 8) = o1;
}

// ---------------- K0: qkv[b,m,n] = sum_k wb[m,k]*xT[b,n,k]  (bf16 MFMA) ----------------
// 128x128 tile, BK=64, 512 threads (8 waves of 32x64), double-buffered LDS,
// counted vmcnt + raw barriers, both-sides XOR chunk swizzle.
__global__ __launch_bounds__(512, 4)
void k_gemm(const unsigned short* __restrict__ wb, const unsigned short* __restrict__ xT,
            unsigned short* __restrict__ qkv){
  const int b  = blockIdx.z;
  const int m0 = blockIdx.y * 128;
  const int n0 = blockIdx.x * 128;
  __shared__ unsigned short As[2][128 * 64];
  __shared__ unsigned short Bs[2][128 * 64];
  const int t = threadIdx.x;
  const int lane = t & 63;
  const int fr = lane & 15;          // fragment row-in-16
  const int ld = lane >> 4;          // 0..3 k-subchunk
  const int w = t >> 6;              // 8 waves: 4x2 of 32x64
  const int wr = w >> 1, wc = w & 1;
  f32x4 acc[2][4];
#pragma unroll
  for (int i = 0; i < 2; ++i)
#pragma unroll
    for (int j = 0; j < 4; ++j) acc[i][j] = (f32x4){0.f,0.f,0.f,0.f};

  const unsigned short* Ag = wb + (size_t)m0 * DIM_;
  const unsigned short* Bg = xT + ((size_t)b * HW_ + n0) * DIM_;

  auto stage = [&](int buf, int k0){
#pragma unroll
    for (int i = 0; i < 2; ++i){
      const int q = i * 512 + t;          // 1024 chunks of 16B
      const int qb = q & ~63;             // wave-uniform base chunk
      const int r = q >> 3, c = q & 7;
      const int cs = c ^ (r & 7);         // pre-swizzled global source
      __builtin_amdgcn_global_load_lds(
        (const __attribute__((address_space(1))) void*)(Ag + (size_t)r * DIM_ + k0 + cs * 8),
        (__attribute__((address_space(3))) void*)(&As[buf][qb * 8]), 16, 0, 0);
    }
#pragma unroll
    for (int i = 0; i < 2; ++i){
      const int q = i * 512 + t;
      const int qb = q & ~63;
      const int r = q >> 3, c = q & 7;
      const int cs = c ^ (r & 7);
      __builtin_amdgcn_global_load_lds(
        (const __attribute__((address_space(1))) void*)(Bg + (size_t)r * DIM_ + k0 + cs * 8),
        (__attribute__((address_space(3))) void*)(&Bs[buf][qb * 8]), 16, 0, 0);
    }
  };

  stage(0, 0);
  for (int it = 0; it < 6; ++it){
    const int cur = it & 1;
    if (it < 5){
      stage(cur ^ 1, (it + 1) * 64);
      asm volatile("s_waitcnt vmcnt(4)" ::: "memory");   // stage(it) done; next 4 in flight
    } else {
      asm volatile("s_waitcnt vmcnt(0)" ::: "memory");
    }
    __builtin_amdgcn_s_barrier();
    asm volatile("" ::: "memory");
#pragma unroll
    for (int ks = 0; ks < 2; ++ks){
      bf16x8 af[2], bfr[4];
#pragma unroll
      for (int mi = 0; mi < 2; ++mi){
        const int row = wr * 32 + mi * 16 + fr;
        const int cc = (ks * 4 + ld) ^ (row & 7);        // swizzled read
        af[mi] = *reinterpret_cast<const bf16x8*>(&As[cur][row * 64 + cc * 8]);
      }
#pragma unroll
      for (int ni = 0; ni < 4; ++ni){
        const int row = wc * 64 + ni * 16 + fr;
        const int cc = (ks * 4 + ld) ^ (row & 7);
        bfr[ni] = *reinterpret_cast<const bf16x8*>(&Bs[cur][row * 64 + cc * 8]);
      }
#pragma unroll
      for (int mi = 0; mi < 2; ++mi)
#pragma unroll
        for (int ni = 0; ni < 4; ++ni)
          acc[mi][ni] = __builtin_amdgcn_mfma_f32_16x16x32_bf16(af[mi], bfr[ni], acc[mi][ni], 0, 0, 0);
    }
    asm volatile("" ::: "memory");
    __builtin_amdgcn_s_barrier();
  }
  unsigned short* yb = qkv + ((size_t)b * CH3 + m0) * HW_ + n0;
#pragma unroll
  for (int mi = 0; mi < 2; ++mi){
    const int rbase = wr * 32 + mi * 16 + (lane >> 4) * 4;
#pragma unroll
    for (int ni = 0; ni < 4; ++ni){
      const int col = wc * 64 + ni * 16 + (lane & 15);
#pragma unroll
      for (int r = 0; r < 4; ++r)
        yb[(size_t)(rbase + r) * HW_ + col] = f2b(acc[mi][ni][r]);
    }
  }
}

// ---------------- K1: dwconv q,k,v; write p=q*k (q-slot) + dv (v-slot); fused stats ----------------
// Stats from raw fp32 conv values (closer to reference); p stored = f2b(aq*ak).
__global__ __launch_bounds__(256)
void k_dwqkv(unsigned short* __restrict__ qkv, const float* __restrict__ w_dw,
             const float* __restrict__ temperature, const float* __restrict__ w_ar,
             float* __restrict__ prm){
  const int pc = blockIdx.x;               // b*384 + ch
  const int ch = pc % DIM_;
  const int b  = pc / DIM_;
  const int d  = ch % D_;
  const int head = ch / D_;
  unsigned short* qp = qkv + ((size_t)b * CH3 + ch) * HW_;
  const unsigned short* kp = qp + (size_t)DIM_ * HW_;
  unsigned short* vp = qp + (size_t)(2 * DIM_) * HW_;
  const int t  = threadIdx.x;
  const int y  = t >> 2;
  const int x0 = (t & 3) * 16;
  float wq9[9], wk9[9], wv9[9];
#pragma unroll
  for (int i = 0; i < 9; ++i){
    wq9[i] = w_dw[ch*9+i];
    wk9[i] = w_dw[(DIM_+ch)*9+i];
    wv9[i] = w_dw[(2*DIM_+ch)*9+i];
  }
  float aq[16], ak[16], av[16];
  dwplane16(qp, wq9, y, x0, aq);
  dwplane16(kp, wk9, y, x0, ak);
  dwplane16(vp, wv9, y, x0, av);
  __shared__ float lds[16];
  float pr[16];
  float sq = 0.f, sk = 0.f, pmx = -3.0e38f, pmn = 3.0e38f;
#pragma unroll
  for (int j = 0; j < 16; ++j){
    sq = fmaf(aq[j], aq[j], sq);
    sk = fmaf(ak[j], ak[j], sk);
    pr[j] = aq[j] * ak[j];
    pmx = fmaxf(pmx, pr[j]); pmn = fminf(pmn, pr[j]);
  }
  block_red4(sq, sk, pmx, pmn, lds);
  const float nq = fmaxf(sqrtf(sq), 1e-12f);
  const float nk = fmaxf(sqrtf(sk), 1e-12f);
  const float c  = temperature[head] / (nq * nk);
  const float m  = (c >= 0.f) ? c * pmx : c * pmn;
  float se = 0.f;
#pragma unroll
  for (int j = 0; j < 16; ++j) se += __expf(fmaf(c, pr[j], -m));
  se = block_red<0>(se, lds);
  // block_red barriers guarantee all q/v neighborhood reads complete before writes
  u16x8 o0, o1;
#pragma unroll
  for (int j = 0; j < 8; ++j){ o0[j] = f2b(pr[j]); o1[j] = f2b(pr[8+j]); }
  *reinterpret_cast<u16x8*>(qp + (size_t)y * IMG + x0)     = o0;
  *reinterpret_cast<u16x8*>(qp + (size_t)y * IMG + x0 + 8) = o1;
#pragma unroll
  for (int j = 0; j < 8; ++j){ o0[j] = f2b(av[j]); o1[j] = f2b(av[8+j]); }
  *reinterpret_cast<u16x8*>(vp + (size_t)y * IMG + x0)     = o0;
  *reinterpret_cast<u16x8*>(vp + (size_t)y * IMG + x0 + 8) = o1;
  if (t == 0){
    prm[pc*4+0] = c;
    prm[pc*4+1] = m;
    prm[pc*4+2] = w_ar[d] / se;
    prm[pc*4+3] = 0.f;
  }
}

// ---------------- K2: a[n] = sum_d (w_ar[d]/se_d) * exp(c_d*p[d,n] - m_d) ----------------
__global__ __launch_bounds__(256)
void k_attn_a(const unsigned short* __restrict__ dqkv, const float* __restrict__ prm,
              float* __restrict__ abuf){
  const int bh   = blockIdx.y;
  const int head = bh & 7, b = bh >> 3;
  const int t = threadIdx.x;
  const int px0 = (blockIdx.x * 256 + t) * 2;
  __shared__ float4 pc[D_];
  if (t < D_) pc[t] = reinterpret_cast<const float4*>(prm)[bh * D_ + t];
  __syncthreads();
  const unsigned short* pbase = dqkv + ((size_t)b * CH3 + head * D_) * HW_ + px0;
  float a0 = 0.f, a1 = 0.f;
  for (int d = 0; d < D_; ++d){
    const uint32_t pv = *reinterpret_cast<const uint32_t*>(pbase + (size_t)d * HW_);
    const float4 pp = pc[d];
    a0 = fmaf(pp.z, __expf(fmaf(pp.x, b2f((unsigned short)pv), -pp.y)), a0);
    a1 = fmaf(pp.z, __expf(fmaf(pp.x, b2f((unsigned short)(pv >> 16)), -pp.y)), a1);
  }
  float2 o; o.x = a0; o.y = a1;
  *reinterpret_cast<float2*>(abuf + (size_t)bh * HW_ + px0) = o;
}

// ---------------- K3: vctx[b,head,d] = sum_n softmax_n(a)[n] * dv[d,n] ----------------
__global__ __launch_bounds__(256)
void k_vctx(const unsigned short* __restrict__ dqkv, const float* __restrict__ abuf,
            float* __restrict__ vctx){
  const int bid  = blockIdx.x;
  const int d    = bid % D_;
  const int head = (bid / D_) % HEADS_;
  const int b    = bid / (D_ * HEADS_);
  const unsigned short* vp = dqkv + ((size_t)b * CH3 + 2*DIM_ + head*D_ + d) * HW_;
  const float* am = abuf + ((size_t)(b * HEADS_ + head)) * HW_;
  __shared__ float lds[16];
  const int t = threadIdx.x;
  float a16[16];
#pragma unroll
  for (int i = 0; i < 4; ++i)
    *reinterpret_cast<float4*>(&a16[i*4]) =
      *reinterpret_cast<const float4*>(am + t*16 + i*4);
  float mx = -3.0e38f;
#pragma unroll
  for (int j = 0; j < 16; ++j) mx = fmaxf(mx, a16[j]);
  mx = block_red<1>(mx, lds);
  float e16[16];
  float sl = 0.f;
#pragma unroll
  for (int j = 0; j < 16; ++j){ e16[j] = __expf(a16[j] - mx); sl += e16[j]; }
  const float S = block_red<0>(sl, lds);
  const float inv = 1.f / S;
  u16x8 v0 = *reinterpret_cast<const u16x8*>(vp + t * 16);
  u16x8 v1 = *reinterpret_cast<const u16x8*>(vp + t * 16 + 8);
  float s = 0.f;
#pragma unroll
  for (int j = 0; j < 8; ++j) s = fmaf(e16[j] * inv,   b2f(v0[j]), s);
#pragma unroll
  for (int j = 0; j < 8; ++j) s = fmaf(e16[8+j] * inv, b2f(v1[j]), s);
  s = block_red<0>(s, lds);
  if (t == 0) vctx[bid] = s;
}

// ---------------- K4: sp[b,h,n] = sigmoid(sum_d u[d]*dv[d,n]) ----------------
__global__ __launch_bounds__(256)
void k_spmask(const unsigned short* __restrict__ dqkv, const float* __restrict__ w_al,
              const float* __restrict__ w_vl, float* __restrict__ spb){
  const int bh   = blockIdx.y;
  const int head = bh & 7, b = bh >> 3;
  const int t = threadIdx.x;
  const int px0 = (blockIdx.x * 256 + t) * 2;
  __shared__ float u[D_];
  __shared__ float avg[DH_];
  if (t < DH_){
    float s = 0.f;
    for (int d = 0; d < D_; ++d) s += w_al[t*D_ + d];
    avg[t] = s * (1.f/(float)HW_);
  }
  __syncthreads();
  if (t == 0){
    float mx = avg[0];
    for (int o = 1; o < DH_; ++o) mx = fmaxf(mx, avg[o]);
    float s = 0.f;
    for (int o = 0; o < DH_; ++o){ avg[o] = expf(avg[o]-mx); s += avg[o]; }
    const float inv = 1.f/s;
    for (int o = 0; o < DH_; ++o) avg[o] *= inv;
  }
  __syncthreads();
  if (t < D_){
    float s = 0.f;
    for (int o = 0; o < DH_; ++o) s = fmaf(avg[o], w_vl[o*D_ + t], s);
    u[t] = s;
  }
  __syncthreads();
  const unsigned short* vb = dqkv + ((size_t)b * CH3 + 2*DIM_ + head*D_) * HW_ + px0;
  float a0 = 0.f, a1 = 0.f;
  for (int d = 0; d < D_; ++d){
    const uint32_t vv = *reinterpret_cast<const uint32_t*>(vb + (size_t)d * HW_);
    const float ud = u[d];
    a0 = fmaf(ud, b2f((unsigned short)vv), a0);
    a1 = fmaf(ud, b2f((unsigned short)(vv >> 16)), a1);
  }
  float2 o;
  o.x = 1.f/(1.f + __expf(-a0));
  o.y = 1.f/(1.f + __expf(-a1));
  *reinterpret_cast<float2*>(spb + (size_t)bh * HW_ + px0) = o;
}

// ---------------- K5: per-b MLP + LayerNorm -> mask_ch[b, c=d*8+head] ----------------
__global__ __launch_bounds__(256)
void k_maskch(const float* __restrict__ vctx, const float* __restrict__ w_vr,
              const float* __restrict__ w_up1, const float* __restrict__ b_up1,
              const float* __restrict__ ln_g, const float* __restrict__ ln_b,
              const float* __restrict__ w_up2, const float* __restrict__ b_up2,
              float* __restrict__ mch){
  const int b = blockIdx.x;
  const int t = threadIdx.x;
  __shared__ float vc[HEADS_*D_];
  __shared__ float cx[HEADS_*DH_];
  __shared__ float t1[D2_*HEADS_];
  __shared__ float lds[16];
  for (int i = t; i < HEADS_*D_; i += 256) vc[i] = vctx[b*HEADS_*D_ + i];
  __syncthreads();
  if (t < HEADS_*DH_){
    const int head = t / DH_, o = t % DH_;
    float s = 0.f;
    for (int d = 0; d < D_; ++d) s = fmaf(w_vr[o*D_+d], vc[head*D_+d], s);
    cx[head*DH_+o] = s;
  }
  __syncthreads();
  const int o2 = t >> 3, hh = t & 7;
  float val = b_up1[o2];
  for (int o = 0; o < DH_; ++o) val = fmaf(w_up1[o2*DH_+o], cx[hh*DH_+o], val);
  const float mu  = block_red<0>(val, lds) * (1.f/256.f);
  const float dv  = val - mu;
  const float var = block_red<0>(dv*dv, lds) * (1.f/256.f);
  float yv = dv / sqrtf(var + 1e-5f);
  yv = fmaf(yv, ln_g[t], ln_b[t]);
  yv = fmaxf(yv, 0.f);
  t1[t] = yv;
  __syncthreads();
  for (int idx = t; idx < D_*HEADS_; idx += 256){
    const int d = idx >> 3, head2 = idx & 7;
    float s = b_up2[d];
    for (int o = 0; o < D2_; ++o) s = fmaf(w_up2[d*D2_+o], t1[o*HEADS_+head2], s);
    mch[b*DIM_ + idx] = 1.f/(1.f + __expf(-s));
  }
}

// ---------------- K6: out = x * (mask_ch + sum_h w_proj*sp) ----------------
__global__ __launch_bounds__(256)
void k_out(const float* __restrict__ x, const float* __restrict__ spb,
           const float* __restrict__ mch, const float* __restrict__ w_proj,
           float* __restrict__ out){
  const int b  = blockIdx.z;
  const int c0 = blockIdx.y * 16;
  const int n  = blockIdx.x * 1024 + threadIdx.x * 4;
  float4 sv[8];
#pragma unroll
  for (int h = 0; h < 8; ++h)
    sv[h] = *reinterpret_cast<const float4*>(spb + ((size_t)(b*8+h))*HW_ + n);
  for (int ci = 0; ci < 16; ++ci){
    const int c = c0 + ci;
    const float g = mch[b*DIM_ + c];
    float4 gv; gv.x = g; gv.y = g; gv.z = g; gv.w = g;
#pragma unroll
    for (int h = 0; h < 8; ++h){
      const float wp = w_proj[c*8+h];
      gv.x = fmaf(wp, sv[h].x, gv.x); gv.y = fmaf(wp, sv[h].y, gv.y);
      gv.z = fmaf(wp, sv[h].z, gv.z); gv.w = fmaf(wp, sv[h].w, gv.w);
    }
    const size_t off = ((size_t)b*DIM_ + c)*HW_ + n;
    float4 xv = *reinterpret_cast<const float4*>(x + off);
    xv.x *= gv.x; xv.y *= gv.y; xv.z *= gv.z; xv.w *= gv.w;
    *reinterpret_cast<float4*>(out + off) = xv;
  }
}

extern "C" void kernel_launch(void* const* d_in, const int* in_sizes, int n_in,
                              void* d_out, int out_size, void* d_ws, size_t ws_size,
                              hipStream_t stream) {
  const float* x      = (const float*)d_in[0];
  const float* w_qkv  = (const float*)d_in[1];
  const float* w_dw   = (const float*)d_in[2];
  const float* temp   = (const float*)d_in[3];
  const float* w_ar   = (const float*)d_in[4];
  const float* w_vr   = (const float*)d_in[5];
  const float* w_up1  = (const float*)d_in[6];
  const float* b_up1  = (const float*)d_in[7];
  const float* ln_g   = (const float*)d_in[8];
  const float* ln_b   = (const float*)d_in[9];
  const float* w_up2  = (const float*)d_in[10];
  const float* b_up2  = (const float*)d_in[11];
  const float* w_al   = (const float*)d_in[12];
  const float* w_vl   = (const float*)d_in[13];
  const float* w_proj = (const float*)d_in[14];
  float* out = (float*)d_out;

  unsigned short* qkvb = (unsigned short*)d_ws;              // 8*1152*4096 bf16
  unsigned short* xT   = qkvb + (size_t)B_*CH3*HW_;          // 8*4096*384 bf16
  unsigned short* wb   = xT + (size_t)B_*HW_*DIM_;           // 1152*384 bf16
  float* prm  = (float*)(wb + (size_t)CH3*DIM_);             // 3072*4
  float* abuf = prm + 4*B_*HEADS_*D_;                        // 64*4096
  float* vctx = abuf + (size_t)B_*HEADS_*HW_;                // 3072
  float* spb  = vctx + B_*HEADS_*D_;                         // 64*4096
  float* mch  = spb + (size_t)B_*HEADS_*HW_;                 // 8*384

  k_prep2<<<dim3(432 + B_*384), 256, 0, stream>>>(x, w_qkv, xT, wb);
  k_gemm<<<dim3(HW_/128, CH3/128, B_), 512, 0, stream>>>(wb, xT, qkvb);
  k_dwqkv<<<dim3(B_*DIM_), 256, 0, stream>>>(qkvb, w_dw, temp, w_ar, prm);
  k_attn_a<<<dim3(8, B_*HEADS_), 256, 0, stream>>>(qkvb, prm, abuf);
  k_vctx<<<dim3(B_*HEADS_*D_), 256, 0, stream>>>(qkvb, abuf, vctx);
  k_spmask<<<dim3(8, B_*HEADS_), 256, 0, stream>>>(qkvb, w_al, w_vl, spb);
  k_maskch<<<dim3(B_), 256, 0, stream>>>(vctx, w_vr, w_up1, b_up1, ln_g, ln_b,
                                         w_up2, b_up2, mch);
  k_out<<<dim3(HW_/1024, DIM_/16, B_), 256, 0, stream>>>(x, spb, mch, w_proj, out);
}

// Round 10
// 221.089 us; speedup vs baseline: 1.3682x; 1.0965x over previous
//
#include <hip/hip_runtime.h>
#include <math.h>
#include <stdint.h>

#define B_     8
#define DIM_   384
#define HEADS_ 8
#define D_     48
#define DH_    24
#define D2_    32
#define HW_    4096
#define IMG    64
#define CH3    1152   // 3*DIM

typedef __attribute__((ext_vector_type(8))) __bf16   bf16x8;
typedef __attribute__((ext_vector_type(4))) float    f32x4;
typedef __attribute__((ext_vector_type(8))) unsigned short u16x8;

__device__ __forceinline__ float b2f(unsigned short h){
  union { uint32_t u; float f; } v; v.u = ((uint32_t)h) << 16; return v.f;
}
// HW RNE bf16 convert — compiler packs pairs into v_cvt_pk_bf16_f32
__device__ __forceinline__ unsigned short f2b(float f){
  return __builtin_bit_cast(unsigned short, (__bf16)f);
}

// ---------------- reduction helpers ----------------
__device__ __forceinline__ float wred_sum(float v){
#pragma unroll
  for (int m = 32; m; m >>= 1) v += __shfl_xor(v, m);
  return v;
}
template<int OP>  // 0=sum 1=max 2=min
__device__ __forceinline__ float block_red(float v, float* lds){
  if (OP == 0) v = wred_sum(v);
  else if (OP == 1){
#pragma unroll
    for (int m = 32; m; m >>= 1) v = fmaxf(v, __shfl_xor(v, m));
  } else {
#pragma unroll
    for (int m = 32; m; m >>= 1) v = fminf(v, __shfl_xor(v, m));
  }
  const int lane = threadIdx.x & 63;
  const int wid  = threadIdx.x >> 6;
  __syncthreads();
  if (lane == 0) lds[wid] = v;
  __syncthreads();
  const int nw = blockDim.x >> 6;
  float r = lds[0];
  for (int i = 1; i < nw; ++i){
    float o = lds[i];
    if (OP == 0) r += o; else if (OP == 1) r = fmaxf(r, o); else r = fminf(r, o);
  }
  return r;
}

// packed {sum,sum} block reduction — ONE barrier round (256 threads)
__device__ __forceinline__ void block_red2(float& s0, float& s1, float* lds){
#pragma unroll
  for (int m = 32; m; m >>= 1){
    s0 += __shfl_xor(s0, m);
    s1 += __shfl_xor(s1, m);
  }
  const int lane = threadIdx.x & 63;
  const int wid  = threadIdx.x >> 6;
  __syncthreads();
  if (lane == 0){ lds[wid*2] = s0; lds[wid*2+1] = s1; }
  __syncthreads();
  s0 = lds[0] + lds[2] + lds[4] + lds[6];
  s1 = lds[1] + lds[3] + lds[5] + lds[7];
}

// ---------------- P0: w_qkv -> bf16  AND  x -> xT bf16 transpose (merged) ----------------
__global__ __launch_bounds__(256)
void k_prep2(const float* __restrict__ x, const float* __restrict__ w,
             unsigned short* __restrict__ xT, unsigned short* __restrict__ wb){
  __shared__ unsigned short Ts[64][66];
  const int t = threadIdx.x;
  if (blockIdx.x < 432){
    const int i = (blockIdx.x * 256 + t) * 4;    // 1152*384 = 432*256*4
    float4 v = *reinterpret_cast<const float4*>(w + i);
    wb[i+0] = f2b(v.x); wb[i+1] = f2b(v.y); wb[i+2] = f2b(v.z); wb[i+3] = f2b(v.w);
    return;
  }
  const int id = blockIdx.x - 432;               // 8*384 tiles
  const int bz = id / 384;
  const int r2 = id % 384;
  const int by = r2 / 64, bx = r2 % 64;
  const float* xb = x + ((size_t)bz * DIM_ + by * 64) * HW_ + bx * 64;
#pragma unroll
  for (int rr = 0; rr < 4; ++rr){
    const int r = (t >> 4) + rr * 16;
    const int c = (t & 15) * 4;
    float4 v = *reinterpret_cast<const float4*>(xb + (size_t)r * HW_ + c);
    Ts[r][c+0] = f2b(v.x); Ts[r][c+1] = f2b(v.y); Ts[r][c+2] = f2b(v.z); Ts[r][c+3] = f2b(v.w);
  }
  __syncthreads();
  const int rn = t >> 2, kc = (t & 3) * 16;
  unsigned short* yb = xT + ((size_t)bz * HW_ + bx * 64 + rn) * DIM_ + by * 64 + kc;
  u16x8 o0, o1;
#pragma unroll
  for (int j = 0; j < 8; ++j){ o0[j] = Ts[kc + j][rn]; o1[j] = Ts[kc + 8 + j][rn]; }
  *reinterpret_cast<u16x8*>(yb)     = o0;
  *reinterpret_cast<u16x8*>(yb + 8) = o1;
}

// ---------------- K0: qkv[b,m,n] = sum_k wb[m,k]*xT[b,n,k]  (bf16 MFMA) ----------------
// 128x128 tile, BK=64, 512 threads (8 waves of 32x64), double-buffered LDS,
// counted vmcnt + raw barriers, both-sides XOR chunk swizzle.
__global__ __launch_bounds__(512, 4)
void k_gemm(const unsigned short* __restrict__ wb, const unsigned short* __restrict__ xT,
            unsigned short* __restrict__ qkv){
  const int b  = blockIdx.z;
  const int m0 = blockIdx.y * 128;
  const int n0 = blockIdx.x * 128;
  __shared__ unsigned short As[2][128 * 64];
  __shared__ unsigned short Bs[2][128 * 64];
  const int t = threadIdx.x;
  const int lane = t & 63;
  const int fr = lane & 15;          // fragment row-in-16
  const int ld = lane >> 4;          // 0..3 k-subchunk
  const int w = t >> 6;              // 8 waves: 4x2 of 32x64
  const int wr = w >> 1, wc = w & 1;
  f32x4 acc[2][4];
#pragma unroll
  for (int i = 0; i < 2; ++i)
#pragma unroll
    for (int j = 0; j < 4; ++j) acc[i][j] = (f32x4){0.f,0.f,0.f,0.f};

  const unsigned short* Ag = wb + (size_t)m0 * DIM_;
  const unsigned short* Bg = xT + ((size_t)b * HW_ + n0) * DIM_;

  auto stage = [&](int buf, int k0){
#pragma unroll
    for (int i = 0; i < 2; ++i){
      const int q = i * 512 + t;          // 1024 chunks of 16B
      const int qb = q & ~63;             // wave-uniform base chunk
      const int r = q >> 3, c = q & 7;
      const int cs = c ^ (r & 7);         // pre-swizzled global source
      __builtin_amdgcn_global_load_lds(
        (const __attribute__((address_space(1))) void*)(Ag + (size_t)r * DIM_ + k0 + cs * 8),
        (__attribute__((address_space(3))) void*)(&As[buf][qb * 8]), 16, 0, 0);
    }
#pragma unroll
    for (int i = 0; i < 2; ++i){
      const int q = i * 512 + t;
      const int qb = q & ~63;
      const int r = q >> 3, c = q & 7;
      const int cs = c ^ (r & 7);
      __builtin_amdgcn_global_load_lds(
        (const __attribute__((address_space(1))) void*)(Bg + (size_t)r * DIM_ + k0 + cs * 8),
        (__attribute__((address_space(3))) void*)(&Bs[buf][qb * 8]), 16, 0, 0);
    }
  };

  stage(0, 0);
  for (int it = 0; it < 6; ++it){
    const int cur = it & 1;
    if (it < 5){
      stage(cur ^ 1, (it + 1) * 64);
      asm volatile("s_waitcnt vmcnt(4)" ::: "memory");   // stage(it) done; next 4 in flight
    } else {
      asm volatile("s_waitcnt vmcnt(0)" ::: "memory");
    }
    __builtin_amdgcn_s_barrier();
    asm volatile("" ::: "memory");
#pragma unroll
    for (int ks = 0; ks < 2; ++ks){
      bf16x8 af[2], bfr[4];
#pragma unroll
      for (int mi = 0; mi < 2; ++mi){
        const int row = wr * 32 + mi * 16 + fr;
        const int cc = (ks * 4 + ld) ^ (row & 7);        // swizzled read
        af[mi] = *reinterpret_cast<const bf16x8*>(&As[cur][row * 64 + cc * 8]);
      }
#pragma unroll
      for (int ni = 0; ni < 4; ++ni){
        const int row = wc * 64 + ni * 16 + fr;
        const int cc = (ks * 4 + ld) ^ (row & 7);
        bfr[ni] = *reinterpret_cast<const bf16x8*>(&Bs[cur][row * 64 + cc * 8]);
      }
#pragma unroll
      for (int mi = 0; mi < 2; ++mi)
#pragma unroll
        for (int ni = 0; ni < 4; ++ni)
          acc[mi][ni] = __builtin_amdgcn_mfma_f32_16x16x32_bf16(af[mi], bfr[ni], acc[mi][ni], 0, 0, 0);
    }
    asm volatile("" ::: "memory");
    __builtin_amdgcn_s_barrier();
  }
  unsigned short* yb = qkv + ((size_t)b * CH3 + m0) * HW_ + n0;
#pragma unroll
  for (int mi = 0; mi < 2; ++mi){
    const int rbase = wr * 32 + mi * 16 + (lane >> 4) * 4;
#pragma unroll
    for (int ni = 0; ni < 4; ++ni){
      const int col = wc * 64 + ni * 16 + (lane & 15);
#pragma unroll
      for (int r = 0; r < 4; ++r)
        yb[(size_t)(rbase + r) * HW_ + col] = f2b(acc[mi][ni][r]);
    }
  }
}

// ---------------- K1: dwconv q,k,v; write p=q*k (q-slot) + dv (v-slot); fused stats ----------------
// All 18 row-vectors loaded upfront (MLP); edges via intra-wave shuffles;
// m = |temperature| (valid shift: |c*p| <= |T| by elementwise Cauchy-Schwarz).
__global__ __launch_bounds__(256, 4)
void k_dwqkv(unsigned short* __restrict__ qkv, const float* __restrict__ w_dw,
             const float* __restrict__ temperature, const float* __restrict__ w_ar,
             float* __restrict__ prm){
  const int pc = blockIdx.x;               // b*384 + ch
  const int ch = pc % DIM_;
  const int b  = pc / DIM_;
  const int d  = ch % D_;
  const int head = ch / D_;
  unsigned short* qp = qkv + ((size_t)b * CH3 + ch) * HW_;
  const unsigned short* kp = qp + (size_t)DIM_ * HW_;
  unsigned short* vp = qp + (size_t)(2 * DIM_) * HW_;
  const int t  = threadIdx.x;
  const int y  = t >> 2;
  const int x0 = (t & 3) * 16;
  float wq9[9], wk9[9], wv9[9];
#pragma unroll
  for (int i = 0; i < 9; ++i){
    wq9[i] = w_dw[ch*9+i];
    wk9[i] = w_dw[(DIM_+ch)*9+i];
    wv9[i] = w_dw[(2*DIM_+ch)*9+i];
  }
  // zero weights of out-of-bounds rows (loads clamp to row 0; finite*0 = 0)
  bool rok[3];
  size_t roff[3];
#pragma unroll
  for (int r = 0; r < 3; ++r){
    const int yy = y + r - 1;
    rok[r]  = (unsigned)yy < (unsigned)IMG;
    roff[r] = (size_t)(rok[r] ? yy : 0) * IMG + x0;
  }
  // ---- issue ALL loads first (27 vec loads in flight) ----
  u16x8 Q0[3], Q1[3], K0[3], K1[3], V0[3], V1[3];
#pragma unroll
  for (int r = 0; r < 3; ++r){
    Q0[r] = *reinterpret_cast<const u16x8*>(qp + roff[r]);
    Q1[r] = *reinterpret_cast<const u16x8*>(qp + roff[r] + 8);
    K0[r] = *reinterpret_cast<const u16x8*>(kp + roff[r]);
    K1[r] = *reinterpret_cast<const u16x8*>(kp + roff[r] + 8);
    V0[r] = *reinterpret_cast<const u16x8*>(vp + roff[r]);
    V1[r] = *reinterpret_cast<const u16x8*>(vp + roff[r] + 8);
  }
  const int xg = t & 3;
  auto accum = [&](const u16x8* C0, const u16x8* C1, const float* w9, float* a16){
#pragma unroll
    for (int j = 0; j < 16; ++j) a16[j] = 0.f;
#pragma unroll
    for (int r = 0; r < 3; ++r){
      const float g  = rok[r] ? 1.f : 0.f;
      const float w0 = w9[r*3+0] * g, w1 = w9[r*3+1] * g, w2 = w9[r*3+2] * g;
      // edges via shuffles: left = lane-1's C1[7]; right = lane+1's C0[0]
      const uint32_t lw = __shfl_up  ((int)__builtin_bit_cast(uint4, C1[r]).w, 1);
      const uint32_t rw0= __shfl_down((int)__builtin_bit_cast(uint4, C0[r]).x, 1);
      float rw[18];
      rw[0]  = (xg > 0) ? b2f((unsigned short)(lw >> 16)) : 0.f;
      rw[17] = (xg < 3) ? b2f((unsigned short)rw0)        : 0.f;
#pragma unroll
      for (int j = 0; j < 8; ++j){ rw[1+j] = b2f(C0[r][j]); rw[9+j] = b2f(C1[r][j]); }
#pragma unroll
      for (int j = 0; j < 16; ++j)
        a16[j] = fmaf(rw[j], w0, fmaf(rw[j+1], w1, fmaf(rw[j+2], w2, a16[j])));
    }
  };
  float aq[16], ak[16], av[16];
  accum(Q0, Q1, wq9, aq);
  accum(K0, K1, wk9, ak);
  accum(V0, V1, wv9, av);
  __shared__ float lds[8];
  float pr[16];
  float sq = 0.f, sk = 0.f;
#pragma unroll
  for (int j = 0; j < 16; ++j){
    sq = fmaf(aq[j], aq[j], sq);
    sk = fmaf(ak[j], ak[j], sk);
    pr[j] = aq[j] * ak[j];
  }
  block_red2(sq, sk, lds);     // barriers also serve as the in-place write hazard sync
  const float T  = temperature[head];
  const float nq = fmaxf(sqrtf(sq), 1e-12f);
  const float nk = fmaxf(sqrtf(sk), 1e-12f);
  const float c  = T / (nq * nk);
  const float m  = fabsf(T);   // |c*p| <= |T| elementwise -> stable shift
  // writes (all reads complete before block_red2's barriers)
  u16x8 o0, o1;
#pragma unroll
  for (int j = 0; j < 8; ++j){ o0[j] = f2b(pr[j]); o1[j] = f2b(pr[8+j]); }
  *reinterpret_cast<u16x8*>(qp + (size_t)y * IMG + x0)     = o0;
  *reinterpret_cast<u16x8*>(qp + (size_t)y * IMG + x0 + 8) = o1;
#pragma unroll
  for (int j = 0; j < 8; ++j){ o0[j] = f2b(av[j]); o1[j] = f2b(av[8+j]); }
  *reinterpret_cast<u16x8*>(vp + (size_t)y * IMG + x0)     = o0;
  *reinterpret_cast<u16x8*>(vp + (size_t)y * IMG + x0 + 8) = o1;
  float se = 0.f;
#pragma unroll
  for (int j = 0; j < 16; ++j) se += __expf(fmaf(c, pr[j], -m));
  se = block_red<0>(se, lds);
  if (t == 0){
    prm[pc*4+0] = c;
    prm[pc*4+1] = m;
    prm[pc*4+2] = w_ar[d] / se;
    prm[pc*4+3] = 0.f;
  }
}

// ---------------- K2: a[n] = sum_d (w_ar[d]/se_d) * exp(c_d*p[d,n] - m_d) ----------------
__global__ __launch_bounds__(256)
void k_attn_a(const unsigned short* __restrict__ dqkv, const float* __restrict__ prm,
              float* __restrict__ abuf){
  const int bh   = blockIdx.y;
  const int head = bh & 7, b = bh >> 3;
  const int t = threadIdx.x;
  const int px0 = (blockIdx.x * 256 + t) * 2;
  __shared__ float4 pc[D_];
  if (t < D_) pc[t] = reinterpret_cast<const float4*>(prm)[bh * D_ + t];
  __syncthreads();
  const unsigned short* pbase = dqkv + ((size_t)b * CH3 + head * D_) * HW_ + px0;
  float a0 = 0.f, a1 = 0.f;
  for (int d = 0; d < D_; ++d){
    const uint32_t pv = *reinterpret_cast<const uint32_t*>(pbase + (size_t)d * HW_);
    const float4 pp = pc[d];
    a0 = fmaf(pp.z, __expf(fmaf(pp.x, b2f((unsigned short)pv), -pp.y)), a0);
    a1 = fmaf(pp.z, __expf(fmaf(pp.x, b2f((unsigned short)(pv >> 16)), -pp.y)), a1);
  }
  float2 o; o.x = a0; o.y = a1;
  *reinterpret_cast<float2*>(abuf + (size_t)bh * HW_ + px0) = o;
}

// ---------------- K3: vctx[b,head,d] = sum_n softmax_n(a)[n] * dv[d,n] ----------------
__global__ __launch_bounds__(256)
void k_vctx(const unsigned short* __restrict__ dqkv, const float* __restrict__ abuf,
            float* __restrict__ vctx){
  const int bid  = blockIdx.x;
  const int d    = bid % D_;
  const int head = (bid / D_) % HEADS_;
  const int b    = bid / (D_ * HEADS_);
  const unsigned short* vp = dqkv + ((size_t)b * CH3 + 2*DIM_ + head*D_ + d) * HW_;
  const float* am = abuf + ((size_t)(b * HEADS_ + head)) * HW_;
  __shared__ float lds[16];
  const int t = threadIdx.x;
  float a16[16];
#pragma unroll
  for (int i = 0; i < 4; ++i)
    *reinterpret_cast<float4*>(&a16[i*4]) =
      *reinterpret_cast<const float4*>(am + t*16 + i*4);
  float mx = -3.0e38f;
#pragma unroll
  for (int j = 0; j < 16; ++j) mx = fmaxf(mx, a16[j]);
  mx = block_red<1>(mx, lds);
  float e16[16];
  float sl = 0.f;
#pragma unroll
  for (int j = 0; j < 16; ++j){ e16[j] = __expf(a16[j] - mx); sl += e16[j]; }
  const float S = block_red<0>(sl, lds);
  const float inv = 1.f / S;
  u16x8 v0 = *reinterpret_cast<const u16x8*>(vp + t * 16);
  u16x8 v1 = *reinterpret_cast<const u16x8*>(vp + t * 16 + 8);
  float s = 0.f;
#pragma unroll
  for (int j = 0; j < 8; ++j) s = fmaf(e16[j] * inv,   b2f(v0[j]), s);
#pragma unroll
  for (int j = 0; j < 8; ++j) s = fmaf(e16[8+j] * inv, b2f(v1[j]), s);
  s = block_red<0>(s, lds);
  if (t == 0) vctx[bid] = s;
}

// ---------------- K4: sp[b,h,n] = sigmoid(sum_d u[d]*dv[d,n]) ----------------
__global__ __launch_bounds__(256)
void k_spmask(const unsigned short* __restrict__ dqkv, const float* __restrict__ w_al,
              const float* __restrict__ w_vl, float* __restrict__ spb){
  const int bh   = blockIdx.y;
  const int head = bh & 7, b = bh >> 3;
  const int t = threadIdx.x;
  const int px0 = (blockIdx.x * 256 + t) * 2;
  __shared__ float u[D_];
  __shared__ float avg[DH_];
  if (t < DH_){
    float s = 0.f;
    for (int d = 0; d < D_; ++d) s += w_al[t*D_ + d];
    avg[t] = s * (1.f/(float)HW_);
  }
  __syncthreads();
  if (t == 0){
    float mx = avg[0];
    for (int o = 1; o < DH_; ++o) mx = fmaxf(mx, avg[o]);
    float s = 0.f;
    for (int o = 0; o < DH_; ++o){ avg[o] = expf(avg[o]-mx); s += avg[o]; }
    const float inv = 1.f/s;
    for (int o = 0; o < DH_; ++o) avg[o] *= inv;
  }
  __syncthreads();
  if (t < D_){
    float s = 0.f;
    for (int o = 0; o < DH_; ++o) s = fmaf(avg[o], w_vl[o*D_ + t], s);
    u[t] = s;
  }
  __syncthreads();
  const unsigned short* vb = dqkv + ((size_t)b * CH3 + 2*DIM_ + head*D_) * HW_ + px0;
  float a0 = 0.f, a1 = 0.f;
  for (int d = 0; d < D_; ++d){
    const uint32_t vv = *reinterpret_cast<const uint32_t*>(vb + (size_t)d * HW_);
    const float ud = u[d];
    a0 = fmaf(ud, b2f((unsigned short)vv), a0);
    a1 = fmaf(ud, b2f((unsigned short)(vv >> 16)), a1);
  }
  float2 o;
  o.x = 1.f/(1.f + __expf(-a0));
  o.y = 1.f/(1.f + __expf(-a1));
  *reinterpret_cast<float2*>(spb + (size_t)bh * HW_ + px0) = o;
}

// ---------------- K5: per-b MLP + LayerNorm -> mask_ch[b, c=d*8+head] ----------------
__global__ __launch_bounds__(256)
void k_maskch(const float* __restrict__ vctx, const float* __restrict__ w_vr,
              const float* __restrict__ w_up1, const float* __restrict__ b_up1,
              const float* __restrict__ ln_g, const float* __restrict__ ln_b,
              const float* __restrict__ w_up2, const float* __restrict__ b_up2,
              float* __restrict__ mch){
  const int b = blockIdx.x;
  const int t = threadIdx.x;
  __shared__ float vc[HEADS_*D_];
  __shared__ float cx[HEADS_*DH_];
  __shared__ float t1[D2_*HEADS_];
  __shared__ float lds[16];
  for (int i = t; i < HEADS_*D_; i += 256) vc[i] = vctx[b*HEADS_*D_ + i];
  __syncthreads();
  if (t < HEADS_*DH_){
    const int head = t / DH_, o = t % DH_;
    float s = 0.f;
    for (int d = 0; d < D_; ++d) s = fmaf(w_vr[o*D_+d], vc[head*D_+d], s);
    cx[head*DH_+o] = s;
  }
  __syncthreads();
  const int o2 = t >> 3, hh = t & 7;
  float val = b_up1[o2];
  for (int o = 0; o < DH_; ++o) val = fmaf(w_up1[o2*DH_+o], cx[hh*DH_+o], val);
  const float mu  = block_red<0>(val, lds) * (1.f/256.f);
  const float dv  = val - mu;
  const float var = block_red<0>(dv*dv, lds) * (1.f/256.f);
  float yv = dv / sqrtf(var + 1e-5f);
  yv = fmaf(yv, ln_g[t], ln_b[t]);
  yv = fmaxf(yv, 0.f);
  t1[t] = yv;
  __syncthreads();
  for (int idx = t; idx < D_*HEADS_; idx += 256){
    const int d = idx >> 3, head2 = idx & 7;
    float s = b_up2[d];
    for (int o = 0; o < D2_; ++o) s = fmaf(w_up2[d*D2_+o], t1[o*HEADS_+head2], s);
    mch[b*DIM_ + idx] = 1.f/(1.f + __expf(-s));
  }
}

// ---------------- K6: out = x * (mask_ch + sum_h w_proj*sp) ----------------
__global__ __launch_bounds__(256)
void k_out(const float* __restrict__ x, const float* __restrict__ spb,
           const float* __restrict__ mch, const float* __restrict__ w_proj,
           float* __restrict__ out){
  const int b  = blockIdx.z;
  const int c0 = blockIdx.y * 16;
  const int n  = blockIdx.x * 1024 + threadIdx.x * 4;
  float4 sv[8];
#pragma unroll
  for (int h = 0; h < 8; ++h)
    sv[h] = *reinterpret_cast<const float4*>(spb + ((size_t)(b*8+h))*HW_ + n);
  for (int ci = 0; ci < 16; ++ci){
    const int c = c0 + ci;
    const float g = mch[b*DIM_ + c];
    float4 gv; gv.x = g; gv.y = g; gv.z = g; gv.w = g;
#pragma unroll
    for (int h = 0; h < 8; ++h){
      const float wp = w_proj[c*8+h];
      gv.x = fmaf(wp, sv[h].x, gv.x); gv.y = fmaf(wp, sv[h].y, gv.y);
      gv.z = fmaf(wp, sv[h].z, gv.z); gv.w = fmaf(wp, sv[h].w, gv.w);
    }
    const size_t off = ((size_t)b*DIM_ + c)*HW_ + n;
    float4 xv = *reinterpret_cast<const float4*>(x + off);
    xv.x *= gv.x; xv.y *= gv.y; xv.z *= gv.z; xv.w *= gv.w;
    *reinterpret_cast<float4*>(out + off) = xv;
  }
}

extern "C" void kernel_launch(void* const* d_in, const int* in_sizes, int n_in,
                              void* d_out, int out_size, void* d_ws, size_t ws_size,
                              hipStream_t stream) {
  const float* x      = (const float*)d_in[0];
  const float* w_qkv  = (const float*)d_in[1];
  const float* w_dw   = (const float*)d_in[2];
  const float* temp   = (const float*)d_in[3];
  const float* w_ar   = (const float*)d_in[4];
  const float* w_vr   = (const float*)d_in[5];
  const float* w_up1  = (const float*)d_in[6];
  const float* b_up1  = (const float*)d_in[7];
  const float* ln_g   = (const float*)d_in[8];
  const float* ln_b   = (const float*)d_in[9];
  const float* w_up2  = (const float*)d_in[10];
  const float* b_up2  = (const float*)d_in[11];
  const float* w_al   = (const float*)d_in[12];
  const float* w_vl   = (const float*)d_in[13];
  const float* w_proj = (const float*)d_in[14];
  float* out = (float*)d_out;

  unsigned short* qkvb = (unsigned short*)d_ws;              // 8*1152*4096 bf16
  unsigned short* xT   = qkvb + (size_t)B_*CH3*HW_;          // 8*4096*384 bf16
  unsigned short* wb   = xT + (size_t)B_*HW_*DIM_;           // 1152*384 bf16
  float* prm  = (float*)(wb + (size_t)CH3*DIM_);             // 3072*4
  float* abuf = prm + 4*B_*HEADS_*D_;                        // 64*4096
  float* vctx = abuf + (size_t)B_*HEADS_*HW_;                // 3072
  float* spb  = vctx + B_*HEADS_*D_;                         // 64*4096
  float* mch  = spb + (size_t)B_*HEADS_*HW_;                 // 8*384

  k_prep2<<<dim3(432 + B_*384), 256, 0, stream>>>(x, w_qkv, xT, wb);
  k_gemm<<<dim3(HW_/128, CH3/128, B_), 512, 0, stream>>>(wb, xT, qkvb);
  k_dwqkv<<<dim3(B_*DIM_), 256, 0, stream>>>(qkvb, w_dw, temp, w_ar, prm);
  k_attn_a<<<dim3(8, B_*HEADS_), 256, 0, stream>>>(qkvb, prm, abuf);
  k_vctx<<<dim3(B_*HEADS_*D_), 256, 0, stream>>>(qkvb, abuf, vctx);
  k_spmask<<<dim3(8, B_*HEADS_), 256, 0, stream>>>(qkvb, w_al, w_vl, spb);
  k_maskch<<<dim3(B_), 256, 0, stream>>>(vctx, w_vr, w_up1, b_up1, ln_g, ln_b,
                                         w_up2, b_up2, mch);
  k_out<<<dim3(HW_/1024, DIM_/16, B_), 256, 0, stream>>>(x, spb, mch, w_proj, out);
}